// Round 2
// baseline (5741.790 us; speedup 1.0000x reference)
//
#include <hip/hip_runtime.h>
#include <hip/hip_bf16.h>

#define B_    4
#define S_    512
#define NS_   8192
#define MAXW  16
#define H_    256
#define NH_   4
#define DH_   64
#define FF_   1024
#define SPB   8
#define NSPAN (B_*NS_)
#define NEGV  (-1.0e9f)

// ---- setup: tr = token_reps + positional encoding (fp32 table in ws) ----
__global__ void prep_tr_kernel(const float* __restrict__ tok,
                               float* __restrict__ tr){
  int idx = blockIdx.x * 256 + threadIdx.x;          // B*S*H elements
  int j = idx & (H_ - 1);
  int p = (idx >> 8) & (S_ - 1);
  double fac = exp((double)((j >> 1) * 2) * (-9.210340371976184 / 256.0));
  double ang = (double)p * fac;
  float pe = (j & 1) ? (float)cos(ang) : (float)sin(ang);
  tr[idx] = tok[idx] + pe;
}

// ---- setup: q = dummy_query @ w_q.T + b_q ; qkvec[h] = q_h^T W_k,h ; qb[h]=q_h.b_k,h ----
__global__ void prep_q_kernel(const float* __restrict__ dq,
                              const float* __restrict__ wq,
                              const float* __restrict__ wk,
                              const float* __restrict__ bqkv,
                              float* __restrict__ qkvec,
                              float* __restrict__ qb){
  __shared__ float q_s[H_];
  int t = threadIdx.x;
  float acc = bqkv[t];                               // b_qkv[0][t]
  for (int j = 0; j < H_; ++j) acc += dq[j] * wq[t*H_ + j];
  q_s[t] = acc;
  __syncthreads();
  for (int h = 0; h < NH_; ++h) {
    float s = 0.f;
    for (int d = 0; d < DH_; ++d) s += q_s[h*DH_ + d] * wk[(h*DH_ + d)*H_ + t];
    qkvec[h*H_ + t] = s;
  }
  if (t < NH_) {
    float s = 0.f;
    for (int d = 0; d < DH_; ++d) s += q_s[t*DH_ + d] * bqkv[H_ + t*DH_ + d];
    qb[t] = s;
  }
}

// ---- main: SPB spans per block, 256 threads ----
__global__ __launch_bounds__(256) void span_main_kernel(
    const float* __restrict__ tr, const float* __restrict__ qkvec,
    const float* __restrict__ qb,
    const int* __restrict__ span_ids, const int* __restrict__ span_masks,
    const float* __restrict__ wv, const float* __restrict__ bqkv,
    const float* __restrict__ wo, const float* __restrict__ bo,
    const float* __restrict__ dq,
    const float* __restrict__ lng, const float* __restrict__ lnb,
    const float* __restrict__ w1, const float* __restrict__ b1,
    const float* __restrict__ w2, const float* __restrict__ b2,
    float* __restrict__ out)
{
  __shared__ __align__(16) float qk_s[NH_][H_];
  __shared__ float qb_s[NH_];
  __shared__ __align__(16) float x_s[MAXW][H_];
  __shared__ float logit_s[NH_][MAXW];
  __shared__ float attn_s[NH_][MAXW];
  __shared__ __align__(16) float pooled_s[NH_][H_];
  __shared__ __align__(16) float ctx_s[H_];
  __shared__ __align__(16) float y_s[SPB][H_];
  __shared__ __align__(16) float f1_s[SPB][FF_];
  __shared__ float red_s[8];

  const int t = threadIdx.x;
  const int l = t & 63;
  const int wave = t >> 6;

  for (int h = 0; h < NH_; ++h) qk_s[h][t] = qkvec[h*H_ + t];
  if (t < NH_) qb_s[t] = qb[t];
  const float gln  = lng[t];
  const float bln  = lnb[t];
  const float bo_v = bo[t] + dq[t];               // b_o + dummy_query residual
  const float bv_v = bqkv[2*H_ + t];              // b_v

  const int gs0 = blockIdx.x * SPB;

  for (int sp = 0; sp < SPB; ++sp) {
    const int gs = gs0 + sp;
    const int b  = gs >> 13;                      // / NS_
    const int st = span_ids[gs*2];
    const int en = span_ids[gs*2 + 1];
    const int mk = span_masks[gs];
    const int len = mk ? (en - st) : 0;

    __syncthreads();                              // protect x_s / red_s reuse
    for (int w = 0; w < MAXW; ++w) {
      int pos = st + w;
      pos = pos < 0 ? 0 : (pos > S_ - 1 ? S_ - 1 : pos);
      x_s[w][t] = (w < len) ? tr[(b*S_ + pos)*H_ + t] : 0.f;
    }
    __syncthreads();

    // logits[h][w]: 4 threads per (h,w), lane-rotated j to avoid bank conflicts
    {
      const int h = wave;
      const int w = (t >> 2) & 15;
      const int p = t & 3;
      const int base = p * DH_;
      float s = 0.f;
      for (int jj = 0; jj < DH_; ++jj) {
        int j = base + ((jj + l) & 63);
        s += qk_s[h][j] * x_s[w][j];
      }
      s += __shfl_xor(s, 1);
      s += __shfl_xor(s, 2);
      if (p == 0) logit_s[h][w] = (w < len) ? (s + qb_s[h]) * 0.125f : NEGV;
    }
    __syncthreads();

    if (t < NH_) {
      float m = -3.4e38f;
      for (int w = 0; w < MAXW; ++w) m = fmaxf(m, logit_s[t][w]);
      float e[MAXW]; float ssum = 0.f;
      for (int w = 0; w < MAXW; ++w) { e[w] = expf(logit_s[t][w] - m); ssum += e[w]; }
      float inv = 1.f / ssum;
      for (int w = 0; w < MAXW; ++w) attn_s[t][w] = e[w] * inv;
    }
    __syncthreads();

    // pooled[h][:] = sum_w attn[h][w] * x[w][:]  (stride-64 j per lane: 2-way banks)
    {
      const int h = wave;
      float a0 = 0.f, a1 = 0.f, a2 = 0.f, a3 = 0.f;
      for (int w = 0; w < MAXW; ++w) {
        float a = attn_s[h][w];
        a0 += a * x_s[w][l];
        a1 += a * x_s[w][l + 64];
        a2 += a * x_s[w][l + 128];
        a3 += a * x_s[w][l + 192];
      }
      pooled_s[h][l]       = a0;
      pooled_s[h][l + 64]  = a1;
      pooled_s[h][l + 128] = a2;
      pooled_s[h][l + 192] = a3;
    }
    __syncthreads();

    // ctx[i] = w_v[i,:] . pooled[head(i)] + b_v[i]
    {
      const int hi = t >> 6;
      float acc = bv_v;
      const float4* wrow = (const float4*)(wv + t*H_);
      for (int c = 0; c < H_/4; ++c) {
        float4 u = wrow[c];
        int j = c * 4;
        acc += u.x*pooled_s[hi][j+0] + u.y*pooled_s[hi][j+1]
             + u.z*pooled_s[hi][j+2] + u.w*pooled_s[hi][j+3];
      }
      ctx_s[t] = acc;
    }
    __syncthreads();

    // out[i] = w_o[i,:] . ctx + b_o[i] + dq[i]; then LayerNorm
    {
      float acc = bo_v;
      const float4* wrow = (const float4*)(wo + t*H_);
      for (int c = 0; c < H_/4; ++c) {
        float4 u = wrow[c];
        int j = c * 4;
        acc += u.x*ctx_s[j+0] + u.y*ctx_s[j+1]
             + u.z*ctx_s[j+2] + u.w*ctx_s[j+3];
      }
      float s1 = acc, s2 = acc*acc;
      for (int off = 32; off; off >>= 1) {
        s1 += __shfl_down(s1, off);
        s2 += __shfl_down(s2, off);
      }
      if (l == 0) { red_s[wave] = s1; red_s[4 + wave] = s2; }
      __syncthreads();
      float m = (red_s[0]+red_s[1]+red_s[2]+red_s[3]) * (1.f/H_);
      float v = (red_s[4]+red_s[5]+red_s[6]+red_s[7]) * (1.f/H_) - m*m;
      v = fmaxf(v, 0.f);
      float y = (acc - m) * rsqrtf(v + 1e-5f) * gln + bln;
      y_s[sp][t] = y;
    }
  }
  __syncthreads();

  // ---- FFN1: f1[sp][j] = relu(y[sp] . w1[:,j] + b1[j]), j = c*256+t ----
  float accA[4][SPB];
  for (int c = 0; c < 4; ++c)
    for (int sp = 0; sp < SPB; ++sp) accA[c][sp] = 0.f;

  for (int i = 0; i < H_; i += 4) {
    float4 yv[SPB];
    for (int sp = 0; sp < SPB; ++sp) yv[sp] = *(const float4*)&y_s[sp][i];
    for (int c = 0; c < 4; ++c) {
      const int col = c*H_ + t;
      float w0 = w1[(i+0)*FF_ + col];
      float wA = w1[(i+1)*FF_ + col];
      float wB = w1[(i+2)*FF_ + col];
      float wC = w1[(i+3)*FF_ + col];
      for (int sp = 0; sp < SPB; ++sp) {
        accA[c][sp] += w0*yv[sp].x + wA*yv[sp].y + wB*yv[sp].z + wC*yv[sp].w;
      }
    }
  }
  for (int c = 0; c < 4; ++c) {
    float bb = b1[c*H_ + t];
    for (int sp = 0; sp < SPB; ++sp)
      f1_s[sp][c*H_ + t] = fmaxf(accA[c][sp] + bb, 0.f);
  }
  __syncthreads();

  // ---- FFN2: f2[sp][t] = f1[sp] . w2[:,t] + b2[t]; residual + LN2; write ----
  float acc2[SPB];
  for (int sp = 0; sp < SPB; ++sp) acc2[sp] = 0.f;
  for (int j = 0; j < FF_; j += 4) {
    float w0 = w2[(j+0)*H_ + t];
    float wA = w2[(j+1)*H_ + t];
    float wB = w2[(j+2)*H_ + t];
    float wC = w2[(j+3)*H_ + t];
    for (int sp = 0; sp < SPB; ++sp) {
      float4 f = *(const float4*)&f1_s[sp][j];
      acc2[sp] += w0*f.x + wA*f.y + wB*f.z + wC*f.w;
    }
  }
  const float b2v = b2[t];
  for (int sp = 0; sp < SPB; ++sp) {
    float val = acc2[sp] + b2v + y_s[sp][t];
    float s1 = val, s2 = val*val;
    for (int off = 32; off; off >>= 1) {
      s1 += __shfl_down(s1, off);
      s2 += __shfl_down(s2, off);
    }
    if (l == 0) { red_s[wave] = s1; red_s[4 + wave] = s2; }
    __syncthreads();
    float m = (red_s[0]+red_s[1]+red_s[2]+red_s[3]) * (1.f/H_);
    float v = (red_s[4]+red_s[5]+red_s[6]+red_s[7]) * (1.f/H_) - m*m;
    v = fmaxf(v, 0.f);
    float y2 = (val - m) * rsqrtf(v + 1e-5f) * gln + bln;
    const int gs = gs0 + sp;
    float o = span_masks[gs] ? y2 : 0.f;
    out[gs*H_ + t] = o;
    __syncthreads();
  }
}

extern "C" void kernel_launch(void* const* d_in, const int* in_sizes, int n_in,
                              void* d_out, int out_size, void* d_ws, size_t ws_size,
                              hipStream_t stream) {
  const float* tok      = (const float*)d_in[0];
  const int* span_ids   = (const int*)d_in[1];
  const int* span_masks = (const int*)d_in[2];
  // d_in[3] = pooling (unused by reference math)
  const float* dq   = (const float*)d_in[4];
  const float* wq   = (const float*)d_in[5];
  const float* wk   = (const float*)d_in[6];
  const float* wv   = (const float*)d_in[7];
  const float* bqkv = (const float*)d_in[8];
  const float* wo   = (const float*)d_in[9];
  const float* bo   = (const float*)d_in[10];
  const float* lng  = (const float*)d_in[11];
  const float* lnb  = (const float*)d_in[12];
  const float* w1   = (const float*)d_in[13];
  const float* b1   = (const float*)d_in[14];
  const float* w2   = (const float*)d_in[15];
  const float* b2   = (const float*)d_in[16];

  float* ws    = (float*)d_ws;
  float* tr    = ws;                       // B*S*H fp32
  float* qkvec = ws + B_*S_*H_;            // NH*H
  float* qbuf  = qkvec + NH_*H_;           // NH

  hipLaunchKernelGGL(prep_tr_kernel, dim3(B_*S_*H_/256), dim3(256), 0, stream, tok, tr);
  hipLaunchKernelGGL(prep_q_kernel, dim3(1), dim3(256), 0, stream,
                     dq, wq, wk, bqkv, qkvec, qbuf);
  hipLaunchKernelGGL(span_main_kernel, dim3(NSPAN/SPB), dim3(256), 0, stream,
                     tr, qkvec, qbuf, span_ids, span_masks,
                     wv, bqkv, wo, bo, dq, lng, lnb, w1, b1, w2, b2,
                     (float*)d_out);
}

// Round 3
// 4595.272 us; speedup vs baseline: 1.2495x; 1.2495x over previous
//
#include <hip/hip_runtime.h>
#include <hip/hip_bf16.h>

#define B_    4
#define S_    512
#define NS_   8192
#define MAXW  16
#define H_    256
#define NH_   4
#define DH_   64
#define FF_   1024
#define SPB   8
#define NSPAN (B_*NS_)
#define NEGV  (-1.0e9f)
#define MT    32        // FFN M-tile (spans per block)

typedef short s16x8 __attribute__((ext_vector_type(8)));
typedef float f32x4 __attribute__((ext_vector_type(4)));

__device__ __forceinline__ unsigned short f2bu(float v){
  __hip_bfloat16 h = __float2bfloat16(v);
  union { __hip_bfloat16 h; unsigned short u; } c; c.h = h; return c.u;
}
__device__ __forceinline__ float bu2f(unsigned short u){
  union { unsigned int i; float f; } c; c.i = ((unsigned int)u) << 16; return c.f;
}

// ---- setup: tr = token_reps + positional encoding (fp32 table in ws) ----
__global__ void prep_tr_kernel(const float* __restrict__ tok,
                               float* __restrict__ tr){
  int idx = blockIdx.x * 256 + threadIdx.x;
  int j = idx & (H_ - 1);
  int p = (idx >> 8) & (S_ - 1);
  double fac = exp((double)((j >> 1) * 2) * (-9.210340371976184 / 256.0));
  double ang = (double)p * fac;
  float pe = (j & 1) ? (float)cos(ang) : (float)sin(ang);
  tr[idx] = tok[idx] + pe;
}

// ---- setup: q = dq @ w_q.T + b_q ; qkvec[h] = q_h^T W_k,h ; qb[h] = q_h . b_k,h ----
__global__ void prep_q_kernel(const float* __restrict__ dq,
                              const float* __restrict__ wq,
                              const float* __restrict__ wk,
                              const float* __restrict__ bqkv,
                              float* __restrict__ qkvec,
                              float* __restrict__ qb){
  __shared__ float q_s[H_];
  int t = threadIdx.x;
  float acc = bqkv[t];
  for (int j = 0; j < H_; ++j) acc += dq[j] * wq[t*H_ + j];
  q_s[t] = acc;
  __syncthreads();
  for (int h = 0; h < NH_; ++h) {
    float s = 0.f;
    for (int d = 0; d < DH_; ++d) s += q_s[h*DH_ + d] * wk[(h*DH_ + d)*H_ + t];
    qkvec[h*H_ + t] = s;
  }
  if (t < NH_) {
    float s = 0.f;
    for (int d = 0; d < DH_; ++d) s += q_s[t*DH_ + d] * bqkv[H_ + t*DH_ + d];
    qb[t] = s;
  }
}

// ---- setup: W1T[n][k] bf16 (n<1024,k<256), W2T[n][k] bf16 (n<256,k<1024) ----
__global__ void prep_w1t_kernel(const float* __restrict__ w1,
                                unsigned short* __restrict__ w1t){
  int idx = blockIdx.x * 256 + threadIdx.x;    // 1024*256
  int n = idx >> 8, k = idx & 255;
  w1t[idx] = f2bu(w1[k*FF_ + n]);
}
__global__ void prep_w2t_kernel(const float* __restrict__ w2,
                                unsigned short* __restrict__ w2t){
  int idx = blockIdx.x * 256 + threadIdx.x;    // 256*1024
  int n = idx >> 10, k = idx & 1023;
  w2t[idx] = f2bu(w2[k*H_ + n]);
}

// ---- attention kernel: per span gather->logits->softmax->pool->ctx->out->LN1 ----
__global__ __launch_bounds__(256) void span_attn_kernel(
    const float* __restrict__ tr, const float* __restrict__ qkvec,
    const float* __restrict__ qb,
    const int* __restrict__ span_ids, const int* __restrict__ span_masks,
    const float* __restrict__ wv, const float* __restrict__ bqkv,
    const float* __restrict__ wo, const float* __restrict__ bo,
    const float* __restrict__ dq,
    const float* __restrict__ lng, const float* __restrict__ lnb,
    unsigned short* __restrict__ yb)
{
  __shared__ __align__(16) float qk_s[NH_][H_];
  __shared__ float qb_s[NH_];
  __shared__ __align__(16) float x_s[MAXW][H_];
  __shared__ float logit_s[NH_][MAXW];
  __shared__ float attn_s[NH_][MAXW];
  __shared__ __align__(16) float pooled_s[NH_][H_];
  __shared__ __align__(16) float ctx_s[H_];
  __shared__ float red_s[8];

  const int t = threadIdx.x;
  const int l = t & 63;
  const int wave = t >> 6;

  for (int h = 0; h < NH_; ++h) qk_s[h][t] = qkvec[h*H_ + t];
  if (t < NH_) qb_s[t] = qb[t];
  const float gln  = lng[t];
  const float bln  = lnb[t];
  const float bo_v = bo[t] + dq[t];
  const float bv_v = bqkv[2*H_ + t];

  const int gs0 = blockIdx.x * SPB;

  for (int sp = 0; sp < SPB; ++sp) {
    const int gs = gs0 + sp;
    const int b  = gs >> 13;
    const int st = span_ids[gs*2];
    const int en = span_ids[gs*2 + 1];
    const int mk = span_masks[gs];
    const int len = mk ? (en - st) : 0;

    __syncthreads();
    for (int w = 0; w < MAXW; ++w) {
      int pos = st + w;
      pos = pos < 0 ? 0 : (pos > S_ - 1 ? S_ - 1 : pos);
      x_s[w][t] = (w < len) ? tr[(b*S_ + pos)*H_ + t] : 0.f;
    }
    __syncthreads();

    // logits[h][w]: 4 threads per (h,w)
    {
      const int h = wave;
      const int w = (t >> 2) & 15;
      const int p = t & 3;
      const int base = p * DH_;
      float s = 0.f;
      for (int jj = 0; jj < DH_; ++jj) {
        int j = base + ((jj + l) & 63);
        s += qk_s[h][j] * x_s[w][j];
      }
      s += __shfl_xor(s, 1);
      s += __shfl_xor(s, 2);
      if (p == 0) logit_s[h][w] = (w < len) ? (s + qb_s[h]) * 0.125f : NEGV;
    }
    __syncthreads();

    // softmax: wave 0, lane = h*16+w
    if (t < 64) {
      const int h = t >> 4, ww = t & 15;
      float lg = logit_s[h][ww];
      float mx = lg;
      mx = fmaxf(mx, __shfl_xor(mx, 1));
      mx = fmaxf(mx, __shfl_xor(mx, 2));
      mx = fmaxf(mx, __shfl_xor(mx, 4));
      mx = fmaxf(mx, __shfl_xor(mx, 8));
      float e = expf(lg - mx);
      float s = e;
      s += __shfl_xor(s, 1); s += __shfl_xor(s, 2);
      s += __shfl_xor(s, 4); s += __shfl_xor(s, 8);
      attn_s[h][ww] = e / s;
    }
    __syncthreads();

    // pooled[h][:] = sum_w attn[h][w] * x[w][:]
    {
      const int h = wave;
      float a0 = 0.f, a1 = 0.f, a2 = 0.f, a3 = 0.f;
      for (int w = 0; w < MAXW; ++w) {
        float a = attn_s[h][w];
        a0 += a * x_s[w][l];
        a1 += a * x_s[w][l + 64];
        a2 += a * x_s[w][l + 128];
        a3 += a * x_s[w][l + 192];
      }
      pooled_s[h][l]       = a0;
      pooled_s[h][l + 64]  = a1;
      pooled_s[h][l + 128] = a2;
      pooled_s[h][l + 192] = a3;
    }
    __syncthreads();

    // ctx[i] = w_v[i,:] . pooled[head(i)] + b_v[i]
    {
      const int hi = t >> 6;
      float acc = bv_v;
      const float4* wrow = (const float4*)(wv + t*H_);
      for (int c = 0; c < H_/4; ++c) {
        float4 u = wrow[c];
        int j = c * 4;
        acc += u.x*pooled_s[hi][j+0] + u.y*pooled_s[hi][j+1]
             + u.z*pooled_s[hi][j+2] + u.w*pooled_s[hi][j+3];
      }
      ctx_s[t] = acc;
    }
    __syncthreads();

    // out[i] = w_o[i,:] . ctx + b_o[i] + dq[i]; LayerNorm1; write y bf16
    {
      float acc = bo_v;
      const float4* wrow = (const float4*)(wo + t*H_);
      for (int c = 0; c < H_/4; ++c) {
        float4 u = wrow[c];
        int j = c * 4;
        acc += u.x*ctx_s[j+0] + u.y*ctx_s[j+1]
             + u.z*ctx_s[j+2] + u.w*ctx_s[j+3];
      }
      float s1 = acc, s2 = acc*acc;
      for (int off = 32; off; off >>= 1) {
        s1 += __shfl_down(s1, off);
        s2 += __shfl_down(s2, off);
      }
      if (l == 0) { red_s[wave] = s1; red_s[4 + wave] = s2; }
      __syncthreads();
      float m = (red_s[0]+red_s[1]+red_s[2]+red_s[3]) * (1.f/H_);
      float v = (red_s[4]+red_s[5]+red_s[6]+red_s[7]) * (1.f/H_) - m*m;
      v = fmaxf(v, 0.f);
      float y = (acc - m) * rsqrtf(v + 1e-5f) * gln + bln;
      yb[gs*H_ + t] = f2bu(y);
    }
  }
}

// ---- FFN kernel: bf16 MFMA GEMMs + residual + LN2 + mask ----
__global__ __launch_bounds__(256) void ffn_kernel(
    const unsigned short* __restrict__ yb,
    const unsigned short* __restrict__ w1t, const float* __restrict__ b1,
    const unsigned short* __restrict__ w2t, const float* __restrict__ b2,
    const float* __restrict__ lng, const float* __restrict__ lnb,
    const int* __restrict__ masks,
    float* __restrict__ out)
{
  __shared__ __align__(16) unsigned short A_s[MT][264];   // y tile bf16, pad 8
  __shared__ __align__(16) unsigned short f1_s[MT][264];  // f1 chunk bf16
  __shared__ float part_s[4][MT][2];

  const int t = threadIdx.x;
  const int l = t & 63;
  const int w = t >> 6;
  const int ln16 = l & 15;
  const int lg = l >> 4;
  const int m0 = blockIdx.x * MT;

  // stage A tile (32 rows x 256 cols bf16)
  #pragma unroll
  for (int j = 0; j < 4; ++j) {
    int idx = t + j*256;                 // 1024 x uint4
    int r = idx >> 5, c4 = idx & 31;
    uint4 u = *(const uint4*)(yb + (m0 + r)*H_ + c4*8);
    *(uint4*)&A_s[r][c4*8] = u;
  }
  __syncthreads();

  f32x4 f2acc[2][4];
  #pragma unroll
  for (int mf = 0; mf < 2; ++mf)
    #pragma unroll
    for (int nf = 0; nf < 4; ++nf)
      f2acc[mf][nf] = (f32x4){0.f, 0.f, 0.f, 0.f};

  for (int nc = 0; nc < 4; ++nc) {
    // GEMM1: f1[m][n'] = A[m][:] . W1T[nc*256+n'][:]
    f32x4 acc[2][4];
    #pragma unroll
    for (int mf = 0; mf < 2; ++mf)
      #pragma unroll
      for (int nf = 0; nf < 4; ++nf)
        acc[mf][nf] = (f32x4){0.f, 0.f, 0.f, 0.f};

    #pragma unroll
    for (int k0 = 0; k0 < 256; k0 += 32) {
      s16x8 a0 = *(const s16x8*)&A_s[ln16][k0 + lg*8];
      s16x8 a1 = *(const s16x8*)&A_s[16 + ln16][k0 + lg*8];
      #pragma unroll
      for (int nf = 0; nf < 4; ++nf) {
        int n = nc*256 + w*64 + nf*16 + ln16;
        s16x8 b = *(const s16x8*)(w1t + n*256 + k0 + lg*8);
        acc[0][nf] = __builtin_amdgcn_mfma_f32_16x16x32_bf16(a0, b, acc[0][nf], 0, 0, 0);
        acc[1][nf] = __builtin_amdgcn_mfma_f32_16x16x32_bf16(a1, b, acc[1][nf], 0, 0, 0);
      }
    }
    __syncthreads();   // prior GEMM2 readers of f1_s done
    #pragma unroll
    for (int nf = 0; nf < 4; ++nf) {
      float bb = b1[nc*256 + w*64 + nf*16 + ln16];
      #pragma unroll
      for (int mf = 0; mf < 2; ++mf)
        #pragma unroll
        for (int r = 0; r < 4; ++r) {
          float v = acc[mf][nf][r] + bb;
          v = fmaxf(v, 0.f);
          f1_s[mf*16 + lg*4 + r][w*64 + nf*16 + ln16] = f2bu(v);
        }
    }
    __syncthreads();
    // GEMM2: accumulate f2 += f1chunk @ W2T[:, chunk k range]
    #pragma unroll
    for (int k0 = 0; k0 < 256; k0 += 32) {
      s16x8 a0 = *(const s16x8*)&f1_s[ln16][k0 + lg*8];
      s16x8 a1 = *(const s16x8*)&f1_s[16 + ln16][k0 + lg*8];
      #pragma unroll
      for (int nf = 0; nf < 4; ++nf) {
        int n = w*64 + nf*16 + ln16;
        s16x8 b = *(const s16x8*)(w2t + n*FF_ + nc*256 + k0 + lg*8);
        f2acc[0][nf] = __builtin_amdgcn_mfma_f32_16x16x32_bf16(a0, b, f2acc[0][nf], 0, 0, 0);
        f2acc[1][nf] = __builtin_amdgcn_mfma_f32_16x16x32_bf16(a1, b, f2acc[1][nf], 0, 0, 0);
      }
    }
  }

  // epilogue: +b2 +resid, LN2 over 256 cols, mask, write
  float b2v[4], gv[4], bvv[4];
  #pragma unroll
  for (int nf = 0; nf < 4; ++nf) {
    int col = w*64 + nf*16 + ln16;
    b2v[nf] = b2[col]; gv[nf] = lng[col]; bvv[nf] = lnb[col];
  }
  float vals[2][4][4];
  #pragma unroll
  for (int mf = 0; mf < 2; ++mf)
    #pragma unroll
    for (int r = 0; r < 4; ++r) {
      int row = mf*16 + lg*4 + r;
      float s1 = 0.f, s2 = 0.f;
      #pragma unroll
      for (int nf = 0; nf < 4; ++nf) {
        float resid = bu2f(A_s[row][w*64 + nf*16 + ln16]);
        float v = f2acc[mf][nf][r] + b2v[nf] + resid;
        vals[mf][r][nf] = v; s1 += v; s2 += v*v;
      }
      s1 += __shfl_xor(s1, 1); s2 += __shfl_xor(s2, 1);
      s1 += __shfl_xor(s1, 2); s2 += __shfl_xor(s2, 2);
      s1 += __shfl_xor(s1, 4); s2 += __shfl_xor(s2, 4);
      s1 += __shfl_xor(s1, 8); s2 += __shfl_xor(s2, 8);
      if (ln16 == 0) { part_s[w][row][0] = s1; part_s[w][row][1] = s2; }
    }
  __syncthreads();
  #pragma unroll
  for (int mf = 0; mf < 2; ++mf)
    #pragma unroll
    for (int r = 0; r < 4; ++r) {
      int row = mf*16 + lg*4 + r;
      int span = m0 + row;
      float s1 = part_s[0][row][0] + part_s[1][row][0] + part_s[2][row][0] + part_s[3][row][0];
      float s2 = part_s[0][row][1] + part_s[1][row][1] + part_s[2][row][1] + part_s[3][row][1];
      float mean = s1 * (1.f/H_);
      float var  = s2 * (1.f/H_) - mean*mean;
      var = fmaxf(var, 0.f);
      float rstd = rsqrtf(var + 1e-5f);
      int mk = masks[span];
      #pragma unroll
      for (int nf = 0; nf < 4; ++nf) {
        int col = w*64 + nf*16 + ln16;
        float yv = (vals[mf][r][nf] - mean) * rstd * gv[nf] + bvv[nf];
        out[span*H_ + col] = mk ? yv : 0.f;
      }
    }
}

extern "C" void kernel_launch(void* const* d_in, const int* in_sizes, int n_in,
                              void* d_out, int out_size, void* d_ws, size_t ws_size,
                              hipStream_t stream) {
  const float* tok      = (const float*)d_in[0];
  const int* span_ids   = (const int*)d_in[1];
  const int* span_masks = (const int*)d_in[2];
  const float* dq   = (const float*)d_in[4];
  const float* wq   = (const float*)d_in[5];
  const float* wk   = (const float*)d_in[6];
  const float* wv   = (const float*)d_in[7];
  const float* bqkv = (const float*)d_in[8];
  const float* wo   = (const float*)d_in[9];
  const float* bo   = (const float*)d_in[10];
  const float* lng  = (const float*)d_in[11];
  const float* lnb  = (const float*)d_in[12];
  const float* w1   = (const float*)d_in[13];
  const float* b1   = (const float*)d_in[14];
  const float* w2   = (const float*)d_in[15];
  const float* b2   = (const float*)d_in[16];

  float* ws    = (float*)d_ws;
  float* tr    = ws;                       // 524288 floats
  float* qkvec = ws + 524288;              // 1024
  float* qbuf  = qkvec + 1024;             // 4 (padded to 8)
  unsigned short* yb  = (unsigned short*)(ws + 525320);   // 32768*256 bf16
  unsigned short* w1t = yb + 8388608;      // 1024*256 bf16
  unsigned short* w2t = w1t + 262144;      // 256*1024 bf16

  hipLaunchKernelGGL(prep_tr_kernel, dim3(B_*S_*H_/256), dim3(256), 0, stream, tok, tr);
  hipLaunchKernelGGL(prep_q_kernel, dim3(1), dim3(256), 0, stream,
                     dq, wq, wk, bqkv, qkvec, qbuf);
  hipLaunchKernelGGL(prep_w1t_kernel, dim3(1024), dim3(256), 0, stream, w1, w1t);
  hipLaunchKernelGGL(prep_w2t_kernel, dim3(1024), dim3(256), 0, stream, w2, w2t);
  hipLaunchKernelGGL(span_attn_kernel, dim3(NSPAN/SPB), dim3(256), 0, stream,
                     tr, qkvec, qbuf, span_ids, span_masks,
                     wv, bqkv, wo, bo, dq, lng, lnb, yb);
  hipLaunchKernelGGL(ffn_kernel, dim3(NSPAN/MT), dim3(256), 0, stream,
                     yb, w1t, b1, w2t, b2, lng, lnb, span_masks,
                     (float*)d_out);
}

// Round 4
// 487.545 us; speedup vs baseline: 11.7769x; 9.4253x over previous
//
#include <hip/hip_runtime.h>
#include <hip/hip_bf16.h>

#define B_    4
#define S_    512
#define NS_   8192
#define MAXW  16
#define H_    256
#define NH_   4
#define DH_   64
#define FF_   1024
#define NSPAN (B_*NS_)
#define NEGV  (-1.0e9f)
#define MT    32        // GEMM M-tile (spans per block)

typedef short s16x8 __attribute__((ext_vector_type(8)));
typedef float f32x4 __attribute__((ext_vector_type(4)));

__device__ __forceinline__ unsigned short f2bu(float v){
  __hip_bfloat16 h = __float2bfloat16(v);
  union { __hip_bfloat16 h; unsigned short u; } c; c.h = h; return c.u;
}
__device__ __forceinline__ float bu2f(unsigned short u){
  union { unsigned int i; float f; } c; c.i = ((unsigned int)u) << 16; return c.f;
}

// ---- setup: tr = token_reps + positional encoding (fp32 table in ws) ----
__global__ void prep_tr_kernel(const float* __restrict__ tok,
                               float* __restrict__ tr){
  int idx = blockIdx.x * 256 + threadIdx.x;
  int j = idx & (H_ - 1);
  int p = (idx >> 8) & (S_ - 1);
  double fac = exp((double)((j >> 1) * 2) * (-9.210340371976184 / 256.0));
  double ang = (double)p * fac;
  float pe = (j & 1) ? (float)cos(ang) : (float)sin(ang);
  tr[idx] = tok[idx] + pe;
}

// ---- setup: q = dq@w_q.T + b_q ; qkvec[h] = q_h^T W_k,h ; qb[h] = q_h . b_k,h ----
__global__ void prep_q_kernel(const float* __restrict__ dq,
                              const float* __restrict__ wq,
                              const float* __restrict__ wk,
                              const float* __restrict__ bqkv,
                              float* __restrict__ qkvec,
                              float* __restrict__ qb){
  __shared__ float q_s[H_];
  int t = threadIdx.x;
  float acc = bqkv[t];
  for (int j = 0; j < H_; ++j) acc += dq[j] * wq[t*H_ + j];
  q_s[t] = acc;
  __syncthreads();
  for (int h = 0; h < NH_; ++h) {
    float s = 0.f;
    for (int d = 0; d < DH_; ++d) s += q_s[h*DH_ + d] * wk[(h*DH_ + d)*H_ + t];
    qkvec[h*H_ + t] = s;
  }
  if (t < NH_) {
    float s = 0.f;
    for (int d = 0; d < DH_; ++d) s += q_s[t*DH_ + d] * bqkv[H_ + t*DH_ + d];
    qb[t] = s;
  }
}

// ---- setup: plain fp32 -> bf16 cast (wv, wo are already [n][k] layout) ----
__global__ void cast_bf16_kernel(const float* __restrict__ src,
                                 unsigned short* __restrict__ dst){
  int idx = blockIdx.x * 256 + threadIdx.x;
  dst[idx] = f2bu(src[idx]);
}

// ---- setup: W1T[n][k] bf16 (n<1024,k<256), W2T[n][k] bf16 (n<256,k<1024) ----
__global__ void prep_w1t_kernel(const float* __restrict__ w1,
                                unsigned short* __restrict__ w1t){
  int idx = blockIdx.x * 256 + threadIdx.x;    // 1024*256
  int n = idx >> 8, k = idx & 255;
  w1t[idx] = f2bu(w1[k*FF_ + n]);
}
__global__ void prep_w2t_kernel(const float* __restrict__ w2,
                                unsigned short* __restrict__ w2t){
  int idx = blockIdx.x * 256 + threadIdx.x;    // 256*1024
  int n = idx >> 10, k = idx & 1023;
  w2t[idx] = f2bu(w2[k*H_ + n]);
}

// ---- pool kernel: one WAVE per span, no block barriers in the hot path ----
// writes pooled[spanL][h*256 + c] = sum_w attn[h][w] * x[w][c]  (bf16)
__global__ __launch_bounds__(256) void pool_kernel(
    const float* __restrict__ tr, const float* __restrict__ qkvec,
    const float* __restrict__ qb,
    const int* __restrict__ span_ids, const int* __restrict__ span_masks,
    int span0, unsigned short* __restrict__ pooled)
{
  __shared__ float qk_s[NH_][264];       // pad: h-stride 264 breaks bank aliasing
  const int t = threadIdx.x;
  const int l = t & 63;
  const int wv = t >> 6;
  qk_s[0][t] = qkvec[t];
  qk_s[1][t] = qkvec[H_ + t];
  qk_s[2][t] = qkvec[2*H_ + t];
  qk_s[3][t] = qkvec[3*H_ + t];
  __syncthreads();

  const int spanL = blockIdx.x * 4 + wv;   // local span index (pooled)
  const int span  = span0 + spanL;         // global span index
  const int b  = span >> 13;
  const int st = span_ids[span*2];
  const int en = span_ids[span*2 + 1];
  const int len = span_masks[span] ? (en - st) : 0;

  // phase 1: logits — lane (h,w)
  const int h = l >> 4, w = l & 15;
  int pos = st + w; pos = pos < 0 ? 0 : (pos > S_-1 ? S_-1 : pos);
  const float4* xr = (const float4*)(tr + (b*S_ + pos)*H_);
  float dot = 0.f;
  #pragma unroll 8
  for (int c = 0; c < H_/4; ++c) {
    float4 u = xr[c];
    dot += u.x*qk_s[h][c*4+0] + u.y*qk_s[h][c*4+1]
         + u.z*qk_s[h][c*4+2] + u.w*qk_s[h][c*4+3];
  }
  float logit = (w < len) ? (dot + qb[h]) * 0.125f : NEGV;
  float mx = logit;
  mx = fmaxf(mx, __shfl_xor(mx, 1));
  mx = fmaxf(mx, __shfl_xor(mx, 2));
  mx = fmaxf(mx, __shfl_xor(mx, 4));
  mx = fmaxf(mx, __shfl_xor(mx, 8));
  float e = expf(logit - mx);              // exp(-1e9) == 0 for invalid w
  float se = e;
  se += __shfl_xor(se, 1); se += __shfl_xor(se, 2);
  se += __shfl_xor(se, 4); se += __shfl_xor(se, 8);
  const float av = e / se;

  // phase 2: pooling — lane l owns cols l*4..l*4+3 for all 4 heads
  float acc[NH_][4];
  #pragma unroll
  for (int hh = 0; hh < NH_; ++hh)
    #pragma unroll
    for (int j = 0; j < 4; ++j) acc[hh][j] = 0.f;

  for (int w2 = 0; w2 < len; ++w2) {       // len is wave-uniform
    int p2 = st + w2; p2 = p2 < 0 ? 0 : (p2 > S_-1 ? S_-1 : p2);
    float4 x = *(const float4*)(tr + (b*S_ + p2)*H_ + l*4);
    #pragma unroll
    for (int hh = 0; hh < NH_; ++hh) {
      float a = __shfl(av, hh*16 + w2);
      acc[hh][0] += a*x.x; acc[hh][1] += a*x.y;
      acc[hh][2] += a*x.z; acc[hh][3] += a*x.w;
    }
  }
  unsigned short* pp = pooled + (size_t)spanL * 1024;
  #pragma unroll
  for (int hh = 0; hh < NH_; ++hh) {
    ushort4 o;
    o.x = f2bu(acc[hh][0]); o.y = f2bu(acc[hh][1]);
    o.z = f2bu(acc[hh][2]); o.w = f2bu(acc[hh][3]);
    *(ushort4*)(pp + hh*256 + l*4) = o;
  }
}

// ---- fused GEMM chain: pooled -> ctx -> out1 -> LN1 -> FFN -> LN2 -> out ----
__global__ __launch_bounds__(256) void fused_gemm_kernel(
    const unsigned short* __restrict__ pooled,
    const unsigned short* __restrict__ wvt,   // [256][256] n-major bf16
    const unsigned short* __restrict__ wot,   // [256][256] n-major bf16
    const float* __restrict__ bqkv, const float* __restrict__ bo,
    const float* __restrict__ dq,
    const unsigned short* __restrict__ w1t, const float* __restrict__ b1,
    const unsigned short* __restrict__ w2t, const float* __restrict__ b2,
    const float* __restrict__ lng, const float* __restrict__ lnb,
    const int* __restrict__ masks, int span0,
    float* __restrict__ out)
{
  __shared__ __align__(16) unsigned short buf_s[MT][264];  // ctx, then f1 chunks
  __shared__ __align__(16) unsigned short y_s[MT][264];    // y (GEMM1 A + residual)
  __shared__ float part_s[4][MT][2];

  const int t = threadIdx.x;
  const int l = t & 63;
  const int w = t >> 6;
  const int ln16 = l & 15;
  const int lg = l >> 4;
  const int m0l = blockIdx.x * MT;
  const int m0g = span0 + m0l;

  f32x4 acc[2][4];

  // ---- GEMM V: ctx[row][col] = pooled[row][head(col)*256 + k] . wv[col][k] + bv
  // head(col) == w because each wave owns cols w*64..w*64+63
  #pragma unroll
  for (int mf = 0; mf < 2; ++mf)
    #pragma unroll
    for (int nf = 0; nf < 4; ++nf) acc[mf][nf] = (f32x4){0.f,0.f,0.f,0.f};

  const unsigned short* pbase = pooled + (size_t)m0l*1024 + w*256;
  #pragma unroll
  for (int k0 = 0; k0 < 256; k0 += 32) {
    s16x8 a0 = *(const s16x8*)(pbase + (size_t)ln16*1024 + k0 + lg*8);
    s16x8 a1 = *(const s16x8*)(pbase + (size_t)(16+ln16)*1024 + k0 + lg*8);
    #pragma unroll
    for (int nf = 0; nf < 4; ++nf) {
      const int n = w*64 + nf*16 + ln16;
      s16x8 bfr = *(const s16x8*)(wvt + n*H_ + k0 + lg*8);
      acc[0][nf] = __builtin_amdgcn_mfma_f32_16x16x32_bf16(a0, bfr, acc[0][nf], 0,0,0);
      acc[1][nf] = __builtin_amdgcn_mfma_f32_16x16x32_bf16(a1, bfr, acc[1][nf], 0,0,0);
    }
  }
  #pragma unroll
  for (int nf = 0; nf < 4; ++nf) {
    const int col = w*64 + nf*16 + ln16;
    const float bvv = bqkv[2*H_ + col];
    #pragma unroll
    for (int mf = 0; mf < 2; ++mf)
      #pragma unroll
      for (int r = 0; r < 4; ++r)
        buf_s[mf*16 + lg*4 + r][col] = f2bu(acc[mf][nf][r] + bvv);
  }
  __syncthreads();

  // ---- GEMM O: z[row][col] = ctx[row][:] . wo[col][:]
  #pragma unroll
  for (int mf = 0; mf < 2; ++mf)
    #pragma unroll
    for (int nf = 0; nf < 4; ++nf) acc[mf][nf] = (f32x4){0.f,0.f,0.f,0.f};
  #pragma unroll
  for (int k0 = 0; k0 < 256; k0 += 32) {
    s16x8 a0 = *(const s16x8*)&buf_s[ln16][k0 + lg*8];
    s16x8 a1 = *(const s16x8*)&buf_s[16+ln16][k0 + lg*8];
    #pragma unroll
    for (int nf = 0; nf < 4; ++nf) {
      const int n = w*64 + nf*16 + ln16;
      s16x8 bfr = *(const s16x8*)(wot + n*H_ + k0 + lg*8);
      acc[0][nf] = __builtin_amdgcn_mfma_f32_16x16x32_bf16(a0, bfr, acc[0][nf], 0,0,0);
      acc[1][nf] = __builtin_amdgcn_mfma_f32_16x16x32_bf16(a1, bfr, acc[1][nf], 0,0,0);
    }
  }

  // ---- + (bo + dq), LN1 -> y_s (bf16) ----
  {
    float bbv[4], glv[4], blv[4];
    #pragma unroll
    for (int nf = 0; nf < 4; ++nf) {
      const int col = w*64 + nf*16 + ln16;
      bbv[nf] = bo[col] + dq[col];
      glv[nf] = lng[col]; blv[nf] = lnb[col];
    }
    float vals[2][4][4];
    #pragma unroll
    for (int mf = 0; mf < 2; ++mf)
      #pragma unroll
      for (int r = 0; r < 4; ++r) {
        const int row = mf*16 + lg*4 + r;
        float s1 = 0.f, s2 = 0.f;
        #pragma unroll
        for (int nf = 0; nf < 4; ++nf) {
          float v = acc[mf][nf][r] + bbv[nf];
          vals[mf][r][nf] = v; s1 += v; s2 += v*v;
        }
        s1 += __shfl_xor(s1,1); s2 += __shfl_xor(s2,1);
        s1 += __shfl_xor(s1,2); s2 += __shfl_xor(s2,2);
        s1 += __shfl_xor(s1,4); s2 += __shfl_xor(s2,4);
        s1 += __shfl_xor(s1,8); s2 += __shfl_xor(s2,8);
        if (ln16 == 0) { part_s[w][row][0] = s1; part_s[w][row][1] = s2; }
      }
    __syncthreads();
    #pragma unroll
    for (int mf = 0; mf < 2; ++mf)
      #pragma unroll
      for (int r = 0; r < 4; ++r) {
        const int row = mf*16 + lg*4 + r;
        float s1 = part_s[0][row][0]+part_s[1][row][0]+part_s[2][row][0]+part_s[3][row][0];
        float s2 = part_s[0][row][1]+part_s[1][row][1]+part_s[2][row][1]+part_s[3][row][1];
        float mean = s1 * (1.f/H_);
        float var  = s2 * (1.f/H_) - mean*mean; var = fmaxf(var, 0.f);
        float rstd = rsqrtf(var + 1e-5f);
        #pragma unroll
        for (int nf = 0; nf < 4; ++nf) {
          const int col = w*64 + nf*16 + ln16;
          y_s[row][col] = f2bu((vals[mf][r][nf] - mean)*rstd*glv[nf] + blv[nf]);
        }
      }
  }
  __syncthreads();

  // ---- FFN: GEMM1 (y @ W1T, relu) chunked -> buf_s; GEMM2 accumulate ----
  f32x4 f2acc[2][4];
  #pragma unroll
  for (int mf = 0; mf < 2; ++mf)
    #pragma unroll
    for (int nf = 0; nf < 4; ++nf) f2acc[mf][nf] = (f32x4){0.f,0.f,0.f,0.f};

  for (int nc = 0; nc < 4; ++nc) {
    #pragma unroll
    for (int mf = 0; mf < 2; ++mf)
      #pragma unroll
      for (int nf = 0; nf < 4; ++nf) acc[mf][nf] = (f32x4){0.f,0.f,0.f,0.f};
    #pragma unroll
    for (int k0 = 0; k0 < 256; k0 += 32) {
      s16x8 a0 = *(const s16x8*)&y_s[ln16][k0 + lg*8];
      s16x8 a1 = *(const s16x8*)&y_s[16+ln16][k0 + lg*8];
      #pragma unroll
      for (int nf = 0; nf < 4; ++nf) {
        const int n = nc*256 + w*64 + nf*16 + ln16;
        s16x8 bfr = *(const s16x8*)(w1t + n*H_ + k0 + lg*8);
        acc[0][nf] = __builtin_amdgcn_mfma_f32_16x16x32_bf16(a0, bfr, acc[0][nf], 0,0,0);
        acc[1][nf] = __builtin_amdgcn_mfma_f32_16x16x32_bf16(a1, bfr, acc[1][nf], 0,0,0);
      }
    }
    __syncthreads();   // prior GEMM2 readers of buf_s done
    #pragma unroll
    for (int nf = 0; nf < 4; ++nf) {
      float bb = b1[nc*256 + w*64 + nf*16 + ln16];
      #pragma unroll
      for (int mf = 0; mf < 2; ++mf)
        #pragma unroll
        for (int r = 0; r < 4; ++r) {
          float v = acc[mf][nf][r] + bb;
          buf_s[mf*16 + lg*4 + r][w*64 + nf*16 + ln16] = f2bu(fmaxf(v, 0.f));
        }
    }
    __syncthreads();
    #pragma unroll
    for (int k0 = 0; k0 < 256; k0 += 32) {
      s16x8 a0 = *(const s16x8*)&buf_s[ln16][k0 + lg*8];
      s16x8 a1 = *(const s16x8*)&buf_s[16+ln16][k0 + lg*8];
      #pragma unroll
      for (int nf = 0; nf < 4; ++nf) {
        const int n = w*64 + nf*16 + ln16;
        s16x8 bfr = *(const s16x8*)(w2t + n*FF_ + nc*256 + k0 + lg*8);
        f2acc[0][nf] = __builtin_amdgcn_mfma_f32_16x16x32_bf16(a0, bfr, f2acc[0][nf], 0,0,0);
        f2acc[1][nf] = __builtin_amdgcn_mfma_f32_16x16x32_bf16(a1, bfr, f2acc[1][nf], 0,0,0);
      }
    }
  }

  // ---- epilogue: +b2 +resid(y), LN2, mask, store ----
  float b2v[4], gv[4], bvv[4];
  #pragma unroll
  for (int nf = 0; nf < 4; ++nf) {
    const int col = w*64 + nf*16 + ln16;
    b2v[nf] = b2[col]; gv[nf] = lng[col]; bvv[nf] = lnb[col];
  }
  float vals[2][4][4];
  #pragma unroll
  for (int mf = 0; mf < 2; ++mf)
    #pragma unroll
    for (int r = 0; r < 4; ++r) {
      const int row = mf*16 + lg*4 + r;
      float s1 = 0.f, s2 = 0.f;
      #pragma unroll
      for (int nf = 0; nf < 4; ++nf) {
        float resid = bu2f(y_s[row][w*64 + nf*16 + ln16]);
        float v = f2acc[mf][nf][r] + b2v[nf] + resid;
        vals[mf][r][nf] = v; s1 += v; s2 += v*v;
      }
      s1 += __shfl_xor(s1,1); s2 += __shfl_xor(s2,1);
      s1 += __shfl_xor(s1,2); s2 += __shfl_xor(s2,2);
      s1 += __shfl_xor(s1,4); s2 += __shfl_xor(s2,4);
      s1 += __shfl_xor(s1,8); s2 += __shfl_xor(s2,8);
      if (ln16 == 0) { part_s[w][row][0] = s1; part_s[w][row][1] = s2; }
    }
  __syncthreads();
  #pragma unroll
  for (int mf = 0; mf < 2; ++mf)
    #pragma unroll
    for (int r = 0; r < 4; ++r) {
      const int row = mf*16 + lg*4 + r;
      const int span = m0g + row;
      float s1 = part_s[0][row][0]+part_s[1][row][0]+part_s[2][row][0]+part_s[3][row][0];
      float s2 = part_s[0][row][1]+part_s[1][row][1]+part_s[2][row][1]+part_s[3][row][1];
      float mean = s1 * (1.f/H_);
      float var  = s2 * (1.f/H_) - mean*mean; var = fmaxf(var, 0.f);
      float rstd = rsqrtf(var + 1e-5f);
      int mk = masks[span];
      #pragma unroll
      for (int nf = 0; nf < 4; ++nf) {
        const int col = w*64 + nf*16 + ln16;
        float yv = (vals[mf][r][nf] - mean)*rstd*gv[nf] + bvv[nf];
        out[(size_t)span*H_ + col] = mk ? yv : 0.f;
      }
    }
}

extern "C" void kernel_launch(void* const* d_in, const int* in_sizes, int n_in,
                              void* d_out, int out_size, void* d_ws, size_t ws_size,
                              hipStream_t stream) {
  const float* tok      = (const float*)d_in[0];
  const int* span_ids   = (const int*)d_in[1];
  const int* span_masks = (const int*)d_in[2];
  const float* dq   = (const float*)d_in[4];
  const float* wq   = (const float*)d_in[5];
  const float* wk   = (const float*)d_in[6];
  const float* wv   = (const float*)d_in[7];
  const float* bqkv = (const float*)d_in[8];
  const float* wo   = (const float*)d_in[9];
  const float* bo   = (const float*)d_in[10];
  const float* lng  = (const float*)d_in[11];
  const float* lnb  = (const float*)d_in[12];
  const float* w1   = (const float*)d_in[13];
  const float* b1   = (const float*)d_in[14];
  const float* w2   = (const float*)d_in[15];
  const float* b2   = (const float*)d_in[16];

  float* ws    = (float*)d_ws;
  float* tr    = ws;                         // 524288 f
  float* qkvec = ws + 524288;                // 1024 f
  float* qbuf  = qkvec + 1024;               // 8 f
  unsigned short* ub = (unsigned short*)(ws + 525320);
  unsigned short* wvt    = ub;               // 65536
  unsigned short* wot    = wvt + 65536;      // 65536
  unsigned short* w1t    = wot + 65536;      // 262144
  unsigned short* w2t    = w1t + 262144;     // 262144
  unsigned short* pooled = w2t + 262144;     // (NSPAN/nb)*1024

  const size_t fixed_bytes = (size_t)525320*4 + (size_t)(65536*2 + 262144*2)*2;
  int nb = 1;
  while (nb < 16 && fixed_bytes + (size_t)(NSPAN/nb)*1024*2 > ws_size) nb <<= 1;
  const int spans_b = NSPAN / nb;

  hipLaunchKernelGGL(prep_tr_kernel, dim3(B_*S_*H_/256), dim3(256), 0, stream, tok, tr);
  hipLaunchKernelGGL(prep_q_kernel, dim3(1), dim3(256), 0, stream,
                     dq, wq, wk, bqkv, qkvec, qbuf);
  hipLaunchKernelGGL(cast_bf16_kernel, dim3(65536/256), dim3(256), 0, stream, wv, wvt);
  hipLaunchKernelGGL(cast_bf16_kernel, dim3(65536/256), dim3(256), 0, stream, wo, wot);
  hipLaunchKernelGGL(prep_w1t_kernel, dim3(262144/256), dim3(256), 0, stream, w1, w1t);
  hipLaunchKernelGGL(prep_w2t_kernel, dim3(262144/256), dim3(256), 0, stream, w2, w2t);

  for (int bi = 0; bi < nb; ++bi) {
    const int span0 = bi * spans_b;
    hipLaunchKernelGGL(pool_kernel, dim3(spans_b/4), dim3(256), 0, stream,
                       tr, qkvec, qbuf, span_ids, span_masks, span0, pooled);
    hipLaunchKernelGGL(fused_gemm_kernel, dim3(spans_b/MT), dim3(256), 0, stream,
                       pooled, wvt, wot, bqkv, bo, dq, w1t, b1, w2t, b2,
                       lng, lnb, span_masks, span0, (float*)d_out);
  }
}

// Round 5
// 409.267 us; speedup vs baseline: 14.0295x; 1.1913x over previous
//
#include <hip/hip_runtime.h>
#include <hip/hip_bf16.h>

#define B_    4
#define S_    512
#define NS_   8192
#define MAXW  16
#define H_    256
#define NH_   4
#define DH_   64
#define FF_   1024
#define NSPAN (B_*NS_)
#define NEGV  (-1.0e9f)
#define MT    64        // GEMM M-tile (spans per block)

typedef short s16x8 __attribute__((ext_vector_type(8)));
typedef float f32x4 __attribute__((ext_vector_type(4)));

__device__ __forceinline__ unsigned short f2bu(float v){
  __hip_bfloat16 h = __float2bfloat16(v);
  union { __hip_bfloat16 h; unsigned short u; } c; c.h = h; return c.u;
}
__device__ __forceinline__ float bu2f(unsigned short u){
  union { unsigned int i; float f; } c; c.i = ((unsigned int)u) << 16; return c.f;
}

// ---- setup: tr = token_reps + positional encoding (fp32 table in ws) ----
__global__ void prep_tr_kernel(const float* __restrict__ tok,
                               float* __restrict__ tr){
  int idx = blockIdx.x * 256 + threadIdx.x;
  int j = idx & (H_ - 1);
  int p = (idx >> 8) & (S_ - 1);
  float fac = expf((float)((j >> 1) * 2) * (-9.210340371976184f / 256.0f));
  float ang = (float)p * fac;
  float pe = (j & 1) ? cosf(ang) : sinf(ang);
  tr[idx] = tok[idx] + pe;
}

// ---- setup: 4 blocks, one per head ----
__global__ void prep_q_kernel(const float* __restrict__ dq,
                              const float* __restrict__ wq,
                              const float* __restrict__ wk,
                              const float* __restrict__ bqkv,
                              float* __restrict__ qkvec,
                              float* __restrict__ qb){
  __shared__ float q_s[H_];
  const int t = threadIdx.x;
  const int h = blockIdx.x;
  float acc = bqkv[t];
  #pragma unroll 8
  for (int j = 0; j < H_; ++j) acc += dq[j] * wq[t*H_ + j];
  q_s[t] = acc;
  __syncthreads();
  float s = 0.f;
  #pragma unroll 8
  for (int d = 0; d < DH_; ++d) s += q_s[h*DH_ + d] * wk[(h*DH_ + d)*H_ + t];
  qkvec[h*H_ + t] = s;
  if (t < 64) {
    float p = q_s[h*DH_ + t] * bqkv[H_ + h*DH_ + t];
    for (int off = 32; off; off >>= 1) p += __shfl_down(p, off);
    if (t == 0) qb[h] = p;
  }
}

// ---- setup: plain fp32 -> bf16 cast (wv, wo are already [n][k] layout) ----
__global__ void cast_bf16_kernel(const float* __restrict__ src,
                                 unsigned short* __restrict__ dst){
  int idx = blockIdx.x * 256 + threadIdx.x;
  dst[idx] = f2bu(src[idx]);
}

// ---- setup: W1T[n][k] bf16 (n<1024,k<256), W2T[n][k] bf16 (n<256,k<1024) ----
__global__ void prep_w1t_kernel(const float* __restrict__ w1,
                                unsigned short* __restrict__ w1t){
  int idx = blockIdx.x * 256 + threadIdx.x;    // 1024*256
  int n = idx >> 8, k = idx & 255;
  w1t[idx] = f2bu(w1[k*FF_ + n]);
}
__global__ void prep_w2t_kernel(const float* __restrict__ w2,
                                unsigned short* __restrict__ w2t){
  int idx = blockIdx.x * 256 + threadIdx.x;    // 256*1024
  int n = idx >> 10, k = idx & 1023;
  w2t[idx] = f2bu(w2[k*H_ + n]);
}

// ---- pool kernel: one WAVE per span ----
__global__ __launch_bounds__(256) void pool_kernel(
    const float* __restrict__ tr, const float* __restrict__ qkvec,
    const float* __restrict__ qb,
    const int* __restrict__ span_ids, const int* __restrict__ span_masks,
    int span0, unsigned short* __restrict__ pooled)
{
  __shared__ float qk_s[NH_][264];
  const int t = threadIdx.x;
  const int l = t & 63;
  const int wv = t >> 6;
  qk_s[0][t] = qkvec[t];
  qk_s[1][t] = qkvec[H_ + t];
  qk_s[2][t] = qkvec[2*H_ + t];
  qk_s[3][t] = qkvec[3*H_ + t];
  __syncthreads();

  const int spanL = blockIdx.x * 4 + wv;
  const int span  = span0 + spanL;
  const int b  = span >> 13;
  const int st = span_ids[span*2];
  const int en = span_ids[span*2 + 1];
  const int len = span_masks[span] ? (en - st) : 0;

  // phase 1: logits — lane (h,w) reads its row (L1 absorbs the 4x reuse)
  const int h = l >> 4, w = l & 15;
  int pos = st + w; pos = pos < 0 ? 0 : (pos > S_-1 ? S_-1 : pos);
  const float4* xr = (const float4*)(tr + (b*S_ + pos)*H_);
  float dot = 0.f;
  #pragma unroll 16
  for (int c = 0; c < H_/4; ++c) {
    float4 u = xr[c];
    dot += u.x*qk_s[h][c*4+0] + u.y*qk_s[h][c*4+1]
         + u.z*qk_s[h][c*4+2] + u.w*qk_s[h][c*4+3];
  }
  float logit = (w < len) ? (dot + qb[h]) * 0.125f : NEGV;
  float mx = logit;
  mx = fmaxf(mx, __shfl_xor(mx, 1));
  mx = fmaxf(mx, __shfl_xor(mx, 2));
  mx = fmaxf(mx, __shfl_xor(mx, 4));
  mx = fmaxf(mx, __shfl_xor(mx, 8));
  float e = expf(logit - mx);
  float se = e;
  se += __shfl_xor(se, 1); se += __shfl_xor(se, 2);
  se += __shfl_xor(se, 4); se += __shfl_xor(se, 8);
  const float av = e / se;

  // phase 2: pooling — lane l owns cols l*4..l*4+3 for all 4 heads
  float acc[NH_][4];
  #pragma unroll
  for (int hh = 0; hh < NH_; ++hh)
    #pragma unroll
    for (int j = 0; j < 4; ++j) acc[hh][j] = 0.f;

  for (int w2 = 0; w2 < len; ++w2) {
    int p2 = st + w2; p2 = p2 < 0 ? 0 : (p2 > S_-1 ? S_-1 : p2);
    float4 x = *(const float4*)(tr + (b*S_ + p2)*H_ + l*4);
    #pragma unroll
    for (int hh = 0; hh < NH_; ++hh) {
      float a = __shfl(av, hh*16 + w2);
      acc[hh][0] += a*x.x; acc[hh][1] += a*x.y;
      acc[hh][2] += a*x.z; acc[hh][3] += a*x.w;
    }
  }
  unsigned short* pp = pooled + (size_t)spanL * 1024;
  #pragma unroll
  for (int hh = 0; hh < NH_; ++hh) {
    ushort4 o;
    o.x = f2bu(acc[hh][0]); o.y = f2bu(acc[hh][1]);
    o.z = f2bu(acc[hh][2]); o.w = f2bu(acc[hh][3]);
    *(ushort4*)(pp + hh*256 + l*4) = o;
  }
}

// ---- register-pipelined GEMM helper: 64-row A, 64-col B slice per wave ----
template <typename AF>
__device__ __forceinline__ void do_gemm(AF aload, const unsigned short* __restrict__ bmat,
                                        int bstr, int koff, f32x4 (&ac)[4][4],
                                        int w, int ln16, int lg)
{
  s16x8 BA[4], BB[4];
  const unsigned short* bb = bmat + koff + lg*8;
  #pragma unroll
  for (int nf = 0; nf < 4; ++nf) {
    const unsigned short* bp = bb + (size_t)(w*64 + nf*16 + ln16)*bstr;
    BA[nf] = *(const s16x8*)bp;
    BB[nf] = *(const s16x8*)(bp + 32);
  }
  #pragma unroll
  for (int kk = 0; kk < 4; ++kk) {
    const int k0 = kk*64;
    {
      s16x8 a0 = aload(0*16 + ln16, k0 + lg*8);
      s16x8 a1 = aload(1*16 + ln16, k0 + lg*8);
      s16x8 a2 = aload(2*16 + ln16, k0 + lg*8);
      s16x8 a3 = aload(3*16 + ln16, k0 + lg*8);
      #pragma unroll
      for (int nf = 0; nf < 4; ++nf) {
        ac[0][nf] = __builtin_amdgcn_mfma_f32_16x16x32_bf16(a0, BA[nf], ac[0][nf], 0,0,0);
        ac[1][nf] = __builtin_amdgcn_mfma_f32_16x16x32_bf16(a1, BA[nf], ac[1][nf], 0,0,0);
        ac[2][nf] = __builtin_amdgcn_mfma_f32_16x16x32_bf16(a2, BA[nf], ac[2][nf], 0,0,0);
        ac[3][nf] = __builtin_amdgcn_mfma_f32_16x16x32_bf16(a3, BA[nf], ac[3][nf], 0,0,0);
      }
    }
    if (kk < 3) {
      #pragma unroll
      for (int nf = 0; nf < 4; ++nf)
        BA[nf] = *(const s16x8*)(bb + (size_t)(w*64 + nf*16 + ln16)*bstr + k0 + 64);
    }
    {
      s16x8 a0 = aload(0*16 + ln16, k0 + 32 + lg*8);
      s16x8 a1 = aload(1*16 + ln16, k0 + 32 + lg*8);
      s16x8 a2 = aload(2*16 + ln16, k0 + 32 + lg*8);
      s16x8 a3 = aload(3*16 + ln16, k0 + 32 + lg*8);
      #pragma unroll
      for (int nf = 0; nf < 4; ++nf) {
        ac[0][nf] = __builtin_amdgcn_mfma_f32_16x16x32_bf16(a0, BB[nf], ac[0][nf], 0,0,0);
        ac[1][nf] = __builtin_amdgcn_mfma_f32_16x16x32_bf16(a1, BB[nf], ac[1][nf], 0,0,0);
        ac[2][nf] = __builtin_amdgcn_mfma_f32_16x16x32_bf16(a2, BB[nf], ac[2][nf], 0,0,0);
        ac[3][nf] = __builtin_amdgcn_mfma_f32_16x16x32_bf16(a3, BB[nf], ac[3][nf], 0,0,0);
      }
    }
    if (kk < 3) {
      #pragma unroll
      for (int nf = 0; nf < 4; ++nf)
        BB[nf] = *(const s16x8*)(bb + (size_t)(w*64 + nf*16 + ln16)*bstr + k0 + 96);
    }
  }
}

// ---- fused GEMM chain: pooled -> ctx -> out1 -> LN1 -> FFN -> LN2 -> out ----
__global__ __launch_bounds__(256) void fused_gemm_kernel(
    const unsigned short* __restrict__ pooled,
    const unsigned short* __restrict__ wvt,   // [256][256] n-major bf16
    const unsigned short* __restrict__ wot,   // [256][256] n-major bf16
    const float* __restrict__ bqkv, const float* __restrict__ bo,
    const float* __restrict__ dq,
    const unsigned short* __restrict__ w1t, const float* __restrict__ b1,
    const unsigned short* __restrict__ w2t, const float* __restrict__ b2,
    const float* __restrict__ lng, const float* __restrict__ lnb,
    const int* __restrict__ masks, int span0,
    float* __restrict__ out)
{
  __shared__ __align__(16) unsigned short buf_s[MT][264];  // ctx, then f1 chunks
  __shared__ __align__(16) unsigned short y_s[MT][264];    // y (residual + FFN A)
  __shared__ float part_s[4][MT][2];

  const int t = threadIdx.x;
  const int l = t & 63;
  const int w = t >> 6;
  const int ln16 = l & 15;
  const int lg = l >> 4;
  const int m0l = blockIdx.x * MT;
  const int m0g = span0 + m0l;

  auto aldP = [&](int r, int kc) -> s16x8 {
    return *(const s16x8*)(pooled + (size_t)(m0l + r)*1024 + w*256 + kc);
  };
  auto aldY = [&](int r, int kc) -> s16x8 { return *(const s16x8*)&y_s[r][kc]; };
  auto aldB = [&](int r, int kc) -> s16x8 { return *(const s16x8*)&buf_s[r][kc]; };

  f32x4 acc[4][4];

  // ---- GEMM V (head(cols of wave w) == w) ----
  #pragma unroll
  for (int mf = 0; mf < 4; ++mf)
    #pragma unroll
    for (int nf = 0; nf < 4; ++nf) acc[mf][nf] = (f32x4){0.f,0.f,0.f,0.f};
  do_gemm(aldP, wvt, 256, 0, acc, w, ln16, lg);
  #pragma unroll
  for (int nf = 0; nf < 4; ++nf) {
    const int col = w*64 + nf*16 + ln16;
    const float bvv = bqkv[2*H_ + col];
    #pragma unroll
    for (int mf = 0; mf < 4; ++mf)
      #pragma unroll
      for (int r = 0; r < 4; ++r)
        buf_s[mf*16 + lg*4 + r][col] = f2bu(acc[mf][nf][r] + bvv);
  }
  __syncthreads();

  // ---- GEMM O ----
  #pragma unroll
  for (int mf = 0; mf < 4; ++mf)
    #pragma unroll
    for (int nf = 0; nf < 4; ++nf) acc[mf][nf] = (f32x4){0.f,0.f,0.f,0.f};
  do_gemm(aldB, wot, 256, 0, acc, w, ln16, lg);

  // ---- + (bo + dq), LN1 -> y_s (bf16) ----
  {
    float bbv[4], glv[4], blv[4];
    #pragma unroll
    for (int nf = 0; nf < 4; ++nf) {
      const int col = w*64 + nf*16 + ln16;
      bbv[nf] = bo[col] + dq[col];
      glv[nf] = lng[col]; blv[nf] = lnb[col];
    }
    float vals[4][4][4];
    #pragma unroll
    for (int mf = 0; mf < 4; ++mf)
      #pragma unroll
      for (int r = 0; r < 4; ++r) {
        const int row = mf*16 + lg*4 + r;
        float s1 = 0.f, s2 = 0.f;
        #pragma unroll
        for (int nf = 0; nf < 4; ++nf) {
          float v = acc[mf][nf][r] + bbv[nf];
          vals[mf][r][nf] = v; s1 += v; s2 += v*v;
        }
        s1 += __shfl_xor(s1,1); s2 += __shfl_xor(s2,1);
        s1 += __shfl_xor(s1,2); s2 += __shfl_xor(s2,2);
        s1 += __shfl_xor(s1,4); s2 += __shfl_xor(s2,4);
        s1 += __shfl_xor(s1,8); s2 += __shfl_xor(s2,8);
        if (ln16 == 0) { part_s[w][row][0] = s1; part_s[w][row][1] = s2; }
      }
    __syncthreads();
    #pragma unroll
    for (int mf = 0; mf < 4; ++mf)
      #pragma unroll
      for (int r = 0; r < 4; ++r) {
        const int row = mf*16 + lg*4 + r;
        float s1 = part_s[0][row][0]+part_s[1][row][0]+part_s[2][row][0]+part_s[3][row][0];
        float s2 = part_s[0][row][1]+part_s[1][row][1]+part_s[2][row][1]+part_s[3][row][1];
        float mean = s1 * (1.f/H_);
        float var  = s2 * (1.f/H_) - mean*mean; var = fmaxf(var, 0.f);
        float rstd = rsqrtf(var + 1e-5f);
        #pragma unroll
        for (int nf = 0; nf < 4; ++nf) {
          const int col = w*64 + nf*16 + ln16;
          y_s[row][col] = f2bu((vals[mf][r][nf] - mean)*rstd*glv[nf] + blv[nf]);
        }
      }
  }
  __syncthreads();

  // ---- FFN ----
  f32x4 f2acc[4][4];
  #pragma unroll
  for (int mf = 0; mf < 4; ++mf)
    #pragma unroll
    for (int nf = 0; nf < 4; ++nf) f2acc[mf][nf] = (f32x4){0.f,0.f,0.f,0.f};

  for (int nc = 0; nc < 4; ++nc) {
    #pragma unroll
    for (int mf = 0; mf < 4; ++mf)
      #pragma unroll
      for (int nf = 0; nf < 4; ++nf) acc[mf][nf] = (f32x4){0.f,0.f,0.f,0.f};
    do_gemm(aldY, w1t + nc*256*H_, 256, 0, acc, w, ln16, lg);
    __syncthreads();   // prior GEMM2 readers of buf_s done
    #pragma unroll
    for (int nf = 0; nf < 4; ++nf) {
      float bb = b1[nc*256 + w*64 + nf*16 + ln16];
      #pragma unroll
      for (int mf = 0; mf < 4; ++mf)
        #pragma unroll
        for (int r = 0; r < 4; ++r)
          buf_s[mf*16 + lg*4 + r][w*64 + nf*16 + ln16] = f2bu(fmaxf(acc[mf][nf][r] + bb, 0.f));
    }
    __syncthreads();
    do_gemm(aldB, w2t, 1024, nc*256, f2acc, w, ln16, lg);
  }

  // ---- epilogue: +b2 +resid(y), LN2, mask, store ----
  float b2v[4], gv[4], bvv[4];
  #pragma unroll
  for (int nf = 0; nf < 4; ++nf) {
    const int col = w*64 + nf*16 + ln16;
    b2v[nf] = b2[col]; gv[nf] = lng[col]; bvv[nf] = lnb[col];
  }
  float vals[4][4][4];
  #pragma unroll
  for (int mf = 0; mf < 4; ++mf)
    #pragma unroll
    for (int r = 0; r < 4; ++r) {
      const int row = mf*16 + lg*4 + r;
      float s1 = 0.f, s2 = 0.f;
      #pragma unroll
      for (int nf = 0; nf < 4; ++nf) {
        float resid = bu2f(y_s[row][w*64 + nf*16 + ln16]);
        float v = f2acc[mf][nf][r] + b2v[nf] + resid;
        vals[mf][r][nf] = v; s1 += v; s2 += v*v;
      }
      s1 += __shfl_xor(s1,1); s2 += __shfl_xor(s2,1);
      s1 += __shfl_xor(s1,2); s2 += __shfl_xor(s2,2);
      s1 += __shfl_xor(s1,4); s2 += __shfl_xor(s2,4);
      s1 += __shfl_xor(s1,8); s2 += __shfl_xor(s2,8);
      if (ln16 == 0) { part_s[w][row][0] = s1; part_s[w][row][1] = s2; }
    }
  __syncthreads();
  #pragma unroll
  for (int mf = 0; mf < 4; ++mf)
    #pragma unroll
    for (int r = 0; r < 4; ++r) {
      const int row = mf*16 + lg*4 + r;
      const int span = m0g + row;
      float s1 = part_s[0][row][0]+part_s[1][row][0]+part_s[2][row][0]+part_s[3][row][0];
      float s2 = part_s[0][row][1]+part_s[1][row][1]+part_s[2][row][1]+part_s[3][row][1];
      float mean = s1 * (1.f/H_);
      float var  = s2 * (1.f/H_) - mean*mean; var = fmaxf(var, 0.f);
      float rstd = rsqrtf(var + 1e-5f);
      int mk = masks[span];
      #pragma unroll
      for (int nf = 0; nf < 4; ++nf) {
        const int col = w*64 + nf*16 + ln16;
        float yv = (vals[mf][r][nf] - mean)*rstd*gv[nf] + bvv[nf];
        out[(size_t)span*H_ + col] = mk ? yv : 0.f;
      }
    }
}

extern "C" void kernel_launch(void* const* d_in, const int* in_sizes, int n_in,
                              void* d_out, int out_size, void* d_ws, size_t ws_size,
                              hipStream_t stream) {
  const float* tok      = (const float*)d_in[0];
  const int* span_ids   = (const int*)d_in[1];
  const int* span_masks = (const int*)d_in[2];
  const float* dq   = (const float*)d_in[4];
  const float* wq   = (const float*)d_in[5];
  const float* wk   = (const float*)d_in[6];
  const float* wv   = (const float*)d_in[7];
  const float* bqkv = (const float*)d_in[8];
  const float* wo   = (const float*)d_in[9];
  const float* bo   = (const float*)d_in[10];
  const float* lng  = (const float*)d_in[11];
  const float* lnb  = (const float*)d_in[12];
  const float* w1   = (const float*)d_in[13];
  const float* b1   = (const float*)d_in[14];
  const float* w2   = (const float*)d_in[15];
  const float* b2   = (const float*)d_in[16];

  float* ws    = (float*)d_ws;
  float* tr    = ws;                         // 524288 f
  float* qkvec = ws + 524288;                // 1024 f
  float* qbuf  = qkvec + 1024;               // 8 f
  unsigned short* ub = (unsigned short*)(ws + 525320);
  unsigned short* wvt    = ub;               // 65536
  unsigned short* wot    = wvt + 65536;      // 65536
  unsigned short* w1t    = wot + 65536;      // 262144
  unsigned short* w2t    = w1t + 262144;     // 262144
  unsigned short* pooled = w2t + 262144;     // (NSPAN/nb)*1024

  const size_t fixed_bytes = (size_t)525320*4 + (size_t)(65536*2 + 262144*2)*2;
  int nb = 1;
  while (nb < 16 && fixed_bytes + (size_t)(NSPAN/nb)*1024*2 > ws_size) nb <<= 1;
  const int spans_b = NSPAN / nb;

  hipLaunchKernelGGL(prep_tr_kernel, dim3(B_*S_*H_/256), dim3(256), 0, stream, tok, tr);
  hipLaunchKernelGGL(prep_q_kernel, dim3(NH_), dim3(256), 0, stream,
                     dq, wq, wk, bqkv, qkvec, qbuf);
  hipLaunchKernelGGL(cast_bf16_kernel, dim3(65536/256), dim3(256), 0, stream, wv, wvt);
  hipLaunchKernelGGL(cast_bf16_kernel, dim3(65536/256), dim3(256), 0, stream, wo, wot);
  hipLaunchKernelGGL(prep_w1t_kernel, dim3(262144/256), dim3(256), 0, stream, w1, w1t);
  hipLaunchKernelGGL(prep_w2t_kernel, dim3(262144/256), dim3(256), 0, stream, w2, w2t);

  for (int bi = 0; bi < nb; ++bi) {
    const int span0 = bi * spans_b;
    hipLaunchKernelGGL(pool_kernel, dim3(spans_b/4), dim3(256), 0, stream,
                       tr, qkvec, qbuf, span_ids, span_masks, span0, pooled);
    hipLaunchKernelGGL(fused_gemm_kernel, dim3(spans_b/MT), dim3(256), 0, stream,
                       pooled, wvt, wot, bqkv, bo, dq, w1t, b1, w2t, b2,
                       lng, lnb, span_masks, span0, (float*)d_out);
  }
}

// Round 6
// 218.369 us; speedup vs baseline: 26.2940x; 1.8742x over previous
//
#include <hip/hip_runtime.h>
#include <hip/hip_bf16.h>

#define B_    4
#define S_    512
#define NS_   8192
#define MAXW  16
#define H_    256
#define NH_   4
#define DH_   64
#define FF_   1024
#define NSPAN (B_*NS_)
#define NEGV  (-1.0e9f)
#define MT    64        // GEMM M-tile (spans per block)

typedef short s16x8 __attribute__((ext_vector_type(8)));
typedef float f32x4 __attribute__((ext_vector_type(4)));

__device__ __forceinline__ unsigned short f2bu(float v){
  __hip_bfloat16 h = __float2bfloat16(v);
  union { __hip_bfloat16 h; unsigned short u; } c; c.h = h; return c.u;
}
__device__ __forceinline__ float bu2f(unsigned short u){
  union { unsigned int i; float f; } c; c.i = ((unsigned int)u) << 16; return c.f;
}

// ---- setup: tr = token_reps + positional encoding (fp32 + bf16 copies) ----
__global__ void prep_tr_kernel(const float* __restrict__ tok,
                               float* __restrict__ tr,
                               unsigned short* __restrict__ trbf){
  int idx = blockIdx.x * 256 + threadIdx.x;
  int j = idx & (H_ - 1);
  int p = (idx >> 8) & (S_ - 1);
  float fac = expf((float)((j >> 1) * 2) * (-9.210340371976184f / 256.0f));
  float ang = (float)p * fac;
  float pe = (j & 1) ? cosf(ang) : sinf(ang);
  float v = tok[idx] + pe;
  tr[idx] = v;
  trbf[idx] = f2bu(v);
}

// ---- setup: 4 blocks (one per head); q computed wave-cooperatively ----
__global__ void prep_q_kernel(const float* __restrict__ dq,
                              const float* __restrict__ wq,
                              const float* __restrict__ wk,
                              const float* __restrict__ bqkv,
                              float* __restrict__ qkvec,
                              float* __restrict__ qb){
  __shared__ float q_s[H_];
  const int t = threadIdx.x;
  const int l = t & 63;
  const int wv = t >> 6;
  const int h = blockIdx.x;
  float4 dqv = *(const float4*)(dq + l*4);
  for (int r = 0; r < 64; ++r) {
    const int row = wv*64 + r;
    float4 wr = *(const float4*)(wq + (size_t)row*H_ + l*4);
    float p = wr.x*dqv.x + wr.y*dqv.y + wr.z*dqv.z + wr.w*dqv.w;
    p += __shfl_xor(p, 1);  p += __shfl_xor(p, 2);
    p += __shfl_xor(p, 4);  p += __shfl_xor(p, 8);
    p += __shfl_xor(p, 16); p += __shfl_xor(p, 32);
    if (l == 0) q_s[row] = p + bqkv[row];
  }
  __syncthreads();
  float s = 0.f;
  #pragma unroll 8
  for (int d = 0; d < DH_; ++d) s += q_s[h*DH_ + d] * wk[(h*DH_ + d)*H_ + t];
  qkvec[h*H_ + t] = s;
  if (t < 64) {
    float p = q_s[h*DH_ + t] * bqkv[H_ + h*DH_ + t];
    for (int off = 32; off; off >>= 1) p += __shfl_down(p, off);
    if (t == 0) qb[h] = p;
  }
}

// ---- setup: per-token logits: lt[row][h] = (qk[h].tr[row] + qb[h])/8 ----
__global__ __launch_bounds__(256) void prep_logit_kernel(
    const float* __restrict__ tr, const float* __restrict__ qkvec,
    const float* __restrict__ qb, float* __restrict__ lt)
{
  const int t = threadIdx.x, l = t & 63, wv = t >> 6;
  const int row = blockIdx.x * 4 + wv;       // b*S + pos, 0..2047
  float4 x = *(const float4*)(tr + (size_t)row*H_ + l*4);
  float p0, p1, p2, p3;
  {
    float4 q0 = *(const float4*)(qkvec + 0*H_ + l*4);
    float4 q1 = *(const float4*)(qkvec + 1*H_ + l*4);
    float4 q2 = *(const float4*)(qkvec + 2*H_ + l*4);
    float4 q3 = *(const float4*)(qkvec + 3*H_ + l*4);
    p0 = q0.x*x.x + q0.y*x.y + q0.z*x.z + q0.w*x.w;
    p1 = q1.x*x.x + q1.y*x.y + q1.z*x.z + q1.w*x.w;
    p2 = q2.x*x.x + q2.y*x.y + q2.z*x.z + q2.w*x.w;
    p3 = q3.x*x.x + q3.y*x.y + q3.z*x.z + q3.w*x.w;
  }
  #pragma unroll
  for (int m = 1; m < 64; m <<= 1) {
    p0 += __shfl_xor(p0, m); p1 += __shfl_xor(p1, m);
    p2 += __shfl_xor(p2, m); p3 += __shfl_xor(p3, m);
  }
  if (l < 4) {
    float pv = (l == 0) ? p0 : (l == 1) ? p1 : (l == 2) ? p2 : p3;
    lt[row*NH_ + l] = (pv + qb[l]) * 0.125f;
  }
}

// ---- setup: plain fp32 -> bf16 cast (wv, wo are already [n][k] layout) ----
__global__ void cast_bf16_kernel(const float* __restrict__ src,
                                 unsigned short* __restrict__ dst){
  int idx = blockIdx.x * 256 + threadIdx.x;
  dst[idx] = f2bu(src[idx]);
}

// ---- setup: W1T[n][k] bf16 (n<1024,k<256), W2T[n][k] bf16 (n<256,k<1024) ----
__global__ void prep_w1t_kernel(const float* __restrict__ w1,
                                unsigned short* __restrict__ w1t){
  int idx = blockIdx.x * 256 + threadIdx.x;    // 1024*256
  int n = idx >> 8, k = idx & 255;
  w1t[idx] = f2bu(w1[k*FF_ + n]);
}
__global__ void prep_w2t_kernel(const float* __restrict__ w2,
                                unsigned short* __restrict__ w2t){
  int idx = blockIdx.x * 256 + threadIdx.x;    // 256*1024
  int n = idx >> 10, k = idx & 1023;
  w2t[idx] = f2bu(w2[k*H_ + n]);
}

// ---- pool kernel v2: one wave per span; gathered logits; unrolled pooling ----
__global__ __launch_bounds__(256) void pool_kernel(
    const unsigned short* __restrict__ trbf,
    const float* __restrict__ lt,
    const int* __restrict__ span_ids, const int* __restrict__ span_masks,
    int span0, unsigned short* __restrict__ pooled)
{
  const int t = threadIdx.x;
  const int l = t & 63;
  const int wv = t >> 6;
  const int spanL = blockIdx.x * 4 + wv;
  const int span  = span0 + spanL;
  const int b  = span >> 13;
  const int st = span_ids[span*2];
  const int en = span_ids[span*2 + 1];
  const int len = span_masks[span] ? (en - st) : 0;

  // softmax over 16 w's per head group (lane = h*16+w)
  const int h = l >> 4, w = l & 15;
  int pos = st + w; pos = pos < 0 ? 0 : (pos > S_-1 ? S_-1 : pos);
  float logit = (w < len) ? lt[(b*S_ + pos)*NH_ + h] : NEGV;
  float mx = logit;
  mx = fmaxf(mx, __shfl_xor(mx, 1));
  mx = fmaxf(mx, __shfl_xor(mx, 2));
  mx = fmaxf(mx, __shfl_xor(mx, 4));
  mx = fmaxf(mx, __shfl_xor(mx, 8));
  float e = expf(logit - mx);
  float se = e;
  se += __shfl_xor(se, 1); se += __shfl_xor(se, 2);
  se += __shfl_xor(se, 4); se += __shfl_xor(se, 8);
  const float av = e / se;        // av == 0 for w >= len (when len > 0)

  // pooling: fixed 16 independent coalesced bf16x4 loads, av masks invalid
  float acc[NH_][4];
  #pragma unroll
  for (int hh = 0; hh < NH_; ++hh)
    #pragma unroll
    for (int j = 0; j < 4; ++j) acc[hh][j] = 0.f;

  const unsigned short* rb = trbf + (size_t)(b*S_)*H_ + l*4;
  #pragma unroll
  for (int w2 = 0; w2 < MAXW; ++w2) {
    int p2 = st + w2; p2 = p2 < 0 ? 0 : (p2 > S_-1 ? S_-1 : p2);
    ushort4 xv = *(const ushort4*)(rb + (size_t)p2*H_);
    float x0 = bu2f(xv.x), x1 = bu2f(xv.y), x2 = bu2f(xv.z), x3 = bu2f(xv.w);
    #pragma unroll
    for (int hh = 0; hh < NH_; ++hh) {
      float a = __shfl(av, hh*16 + w2);
      acc[hh][0] += a*x0; acc[hh][1] += a*x1;
      acc[hh][2] += a*x2; acc[hh][3] += a*x3;
    }
  }
  unsigned short* pp = pooled + (size_t)spanL * 1024;
  #pragma unroll
  for (int hh = 0; hh < NH_; ++hh) {
    ushort4 o;
    o.x = f2bu(acc[hh][0]); o.y = f2bu(acc[hh][1]);
    o.z = f2bu(acc[hh][2]); o.w = f2bu(acc[hh][3]);
    *(ushort4*)(pp + hh*256 + l*4) = o;
  }
}

// ---- register-pipelined GEMM helper: 64-row A, 64-col B slice per wave ----
template <typename AF>
__device__ __forceinline__ void do_gemm(AF aload, const unsigned short* __restrict__ bmat,
                                        int bstr, int koff, f32x4 (&ac)[4][4],
                                        int w, int ln16, int lg)
{
  s16x8 BA[4], BB[4];
  const unsigned short* bb = bmat + koff + lg*8;
  #pragma unroll
  for (int nf = 0; nf < 4; ++nf) {
    const unsigned short* bp = bb + (size_t)(w*64 + nf*16 + ln16)*bstr;
    BA[nf] = *(const s16x8*)bp;
    BB[nf] = *(const s16x8*)(bp + 32);
  }
  #pragma unroll
  for (int kk = 0; kk < 4; ++kk) {
    const int k0 = kk*64;
    {
      s16x8 a0 = aload(0*16 + ln16, k0 + lg*8);
      s16x8 a1 = aload(1*16 + ln16, k0 + lg*8);
      s16x8 a2 = aload(2*16 + ln16, k0 + lg*8);
      s16x8 a3 = aload(3*16 + ln16, k0 + lg*8);
      #pragma unroll
      for (int nf = 0; nf < 4; ++nf) {
        ac[0][nf] = __builtin_amdgcn_mfma_f32_16x16x32_bf16(a0, BA[nf], ac[0][nf], 0,0,0);
        ac[1][nf] = __builtin_amdgcn_mfma_f32_16x16x32_bf16(a1, BA[nf], ac[1][nf], 0,0,0);
        ac[2][nf] = __builtin_amdgcn_mfma_f32_16x16x32_bf16(a2, BA[nf], ac[2][nf], 0,0,0);
        ac[3][nf] = __builtin_amdgcn_mfma_f32_16x16x32_bf16(a3, BA[nf], ac[3][nf], 0,0,0);
      }
    }
    if (kk < 3) {
      #pragma unroll
      for (int nf = 0; nf < 4; ++nf)
        BA[nf] = *(const s16x8*)(bb + (size_t)(w*64 + nf*16 + ln16)*bstr + k0 + 64);
    }
    {
      s16x8 a0 = aload(0*16 + ln16, k0 + 32 + lg*8);
      s16x8 a1 = aload(1*16 + ln16, k0 + 32 + lg*8);
      s16x8 a2 = aload(2*16 + ln16, k0 + 32 + lg*8);
      s16x8 a3 = aload(3*16 + ln16, k0 + 32 + lg*8);
      #pragma unroll
      for (int nf = 0; nf < 4; ++nf) {
        ac[0][nf] = __builtin_amdgcn_mfma_f32_16x16x32_bf16(a0, BB[nf], ac[0][nf], 0,0,0);
        ac[1][nf] = __builtin_amdgcn_mfma_f32_16x16x32_bf16(a1, BB[nf], ac[1][nf], 0,0,0);
        ac[2][nf] = __builtin_amdgcn_mfma_f32_16x16x32_bf16(a2, BB[nf], ac[2][nf], 0,0,0);
        ac[3][nf] = __builtin_amdgcn_mfma_f32_16x16x32_bf16(a3, BB[nf], ac[3][nf], 0,0,0);
      }
    }
    if (kk < 3) {
      #pragma unroll
      for (int nf = 0; nf < 4; ++nf)
        BB[nf] = *(const s16x8*)(bb + (size_t)(w*64 + nf*16 + ln16)*bstr + k0 + 96);
    }
  }
}

// ---- fused GEMM chain: pooled -> ctx -> out1 -> LN1 -> FFN -> LN2 -> out ----
__global__ __launch_bounds__(256) void fused_gemm_kernel(
    const unsigned short* __restrict__ pooled,
    const unsigned short* __restrict__ wvt,   // [256][256] n-major bf16
    const unsigned short* __restrict__ wot,   // [256][256] n-major bf16
    const float* __restrict__ bqkv, const float* __restrict__ bo,
    const float* __restrict__ dq,
    const unsigned short* __restrict__ w1t, const float* __restrict__ b1,
    const unsigned short* __restrict__ w2t, const float* __restrict__ b2,
    const float* __restrict__ lng, const float* __restrict__ lnb,
    const int* __restrict__ masks, int span0,
    float* __restrict__ out)
{
  __shared__ __align__(16) unsigned short buf_s[MT][264];  // ctx, then f1 chunks
  __shared__ __align__(16) unsigned short y_s[MT][264];    // y (residual + FFN A)
  __shared__ float part_s[4][MT][2];

  const int t = threadIdx.x;
  const int l = t & 63;
  const int w = t >> 6;
  const int ln16 = l & 15;
  const int lg = l >> 4;
  const int m0l = blockIdx.x * MT;
  const int m0g = span0 + m0l;

  auto aldP = [&](int r, int kc) -> s16x8 {
    return *(const s16x8*)(pooled + (size_t)(m0l + r)*1024 + w*256 + kc);
  };
  auto aldY = [&](int r, int kc) -> s16x8 { return *(const s16x8*)&y_s[r][kc]; };
  auto aldB = [&](int r, int kc) -> s16x8 { return *(const s16x8*)&buf_s[r][kc]; };

  f32x4 acc[4][4];

  // ---- GEMM V (head(cols of wave w) == w) ----
  #pragma unroll
  for (int mf = 0; mf < 4; ++mf)
    #pragma unroll
    for (int nf = 0; nf < 4; ++nf) acc[mf][nf] = (f32x4){0.f,0.f,0.f,0.f};
  do_gemm(aldP, wvt, 256, 0, acc, w, ln16, lg);
  #pragma unroll
  for (int nf = 0; nf < 4; ++nf) {
    const int col = w*64 + nf*16 + ln16;
    const float bvv = bqkv[2*H_ + col];
    #pragma unroll
    for (int mf = 0; mf < 4; ++mf)
      #pragma unroll
      for (int r = 0; r < 4; ++r)
        buf_s[mf*16 + lg*4 + r][col] = f2bu(acc[mf][nf][r] + bvv);
  }
  __syncthreads();

  // ---- GEMM O ----
  #pragma unroll
  for (int mf = 0; mf < 4; ++mf)
    #pragma unroll
    for (int nf = 0; nf < 4; ++nf) acc[mf][nf] = (f32x4){0.f,0.f,0.f,0.f};
  do_gemm(aldB, wot, 256, 0, acc, w, ln16, lg);

  // ---- + (bo + dq), LN1 -> y_s (bf16) ----
  {
    float bbv[4], glv[4], blv[4];
    #pragma unroll
    for (int nf = 0; nf < 4; ++nf) {
      const int col = w*64 + nf*16 + ln16;
      bbv[nf] = bo[col] + dq[col];
      glv[nf] = lng[col]; blv[nf] = lnb[col];
    }
    float vals[4][4][4];
    #pragma unroll
    for (int mf = 0; mf < 4; ++mf)
      #pragma unroll
      for (int r = 0; r < 4; ++r) {
        const int row = mf*16 + lg*4 + r;
        float s1 = 0.f, s2 = 0.f;
        #pragma unroll
        for (int nf = 0; nf < 4; ++nf) {
          float v = acc[mf][nf][r] + bbv[nf];
          vals[mf][r][nf] = v; s1 += v; s2 += v*v;
        }
        s1 += __shfl_xor(s1,1); s2 += __shfl_xor(s2,1);
        s1 += __shfl_xor(s1,2); s2 += __shfl_xor(s2,2);
        s1 += __shfl_xor(s1,4); s2 += __shfl_xor(s2,4);
        s1 += __shfl_xor(s1,8); s2 += __shfl_xor(s2,8);
        if (ln16 == 0) { part_s[w][row][0] = s1; part_s[w][row][1] = s2; }
      }
    __syncthreads();
    #pragma unroll
    for (int mf = 0; mf < 4; ++mf)
      #pragma unroll
      for (int r = 0; r < 4; ++r) {
        const int row = mf*16 + lg*4 + r;
        float s1 = part_s[0][row][0]+part_s[1][row][0]+part_s[2][row][0]+part_s[3][row][0];
        float s2 = part_s[0][row][1]+part_s[1][row][1]+part_s[2][row][1]+part_s[3][row][1];
        float mean = s1 * (1.f/H_);
        float var  = s2 * (1.f/H_) - mean*mean; var = fmaxf(var, 0.f);
        float rstd = rsqrtf(var + 1e-5f);
        #pragma unroll
        for (int nf = 0; nf < 4; ++nf) {
          const int col = w*64 + nf*16 + ln16;
          y_s[row][col] = f2bu((vals[mf][r][nf] - mean)*rstd*glv[nf] + blv[nf]);
        }
      }
  }
  __syncthreads();

  // ---- FFN ----
  f32x4 f2acc[4][4];
  #pragma unroll
  for (int mf = 0; mf < 4; ++mf)
    #pragma unroll
    for (int nf = 0; nf < 4; ++nf) f2acc[mf][nf] = (f32x4){0.f,0.f,0.f,0.f};

  for (int nc = 0; nc < 4; ++nc) {
    #pragma unroll
    for (int mf = 0; mf < 4; ++mf)
      #pragma unroll
      for (int nf = 0; nf < 4; ++nf) acc[mf][nf] = (f32x4){0.f,0.f,0.f,0.f};
    do_gemm(aldY, w1t + nc*256*H_, 256, 0, acc, w, ln16, lg);
    __syncthreads();   // prior GEMM2 readers of buf_s done
    #pragma unroll
    for (int nf = 0; nf < 4; ++nf) {
      float bb = b1[nc*256 + w*64 + nf*16 + ln16];
      #pragma unroll
      for (int mf = 0; mf < 4; ++mf)
        #pragma unroll
        for (int r = 0; r < 4; ++r)
          buf_s[mf*16 + lg*4 + r][w*64 + nf*16 + ln16] = f2bu(fmaxf(acc[mf][nf][r] + bb, 0.f));
    }
    __syncthreads();
    do_gemm(aldB, w2t, 1024, nc*256, f2acc, w, ln16, lg);
  }

  // ---- epilogue: +b2 +resid(y), LN2, mask, store ----
  float b2v[4], gv[4], bvv[4];
  #pragma unroll
  for (int nf = 0; nf < 4; ++nf) {
    const int col = w*64 + nf*16 + ln16;
    b2v[nf] = b2[col]; gv[nf] = lng[col]; bvv[nf] = lnb[col];
  }
  float vals[4][4][4];
  #pragma unroll
  for (int mf = 0; mf < 4; ++mf)
    #pragma unroll
    for (int r = 0; r < 4; ++r) {
      const int row = mf*16 + lg*4 + r;
      float s1 = 0.f, s2 = 0.f;
      #pragma unroll
      for (int nf = 0; nf < 4; ++nf) {
        float resid = bu2f(y_s[row][w*64 + nf*16 + ln16]);
        float v = f2acc[mf][nf][r] + b2v[nf] + resid;
        vals[mf][r][nf] = v; s1 += v; s2 += v*v;
      }
      s1 += __shfl_xor(s1,1); s2 += __shfl_xor(s2,1);
      s1 += __shfl_xor(s1,2); s2 += __shfl_xor(s2,2);
      s1 += __shfl_xor(s1,4); s2 += __shfl_xor(s2,4);
      s1 += __shfl_xor(s1,8); s2 += __shfl_xor(s2,8);
      if (ln16 == 0) { part_s[w][row][0] = s1; part_s[w][row][1] = s2; }
    }
  __syncthreads();
  #pragma unroll
  for (int mf = 0; mf < 4; ++mf)
    #pragma unroll
    for (int r = 0; r < 4; ++r) {
      const int row = mf*16 + lg*4 + r;
      const int span = m0g + row;
      float s1 = part_s[0][row][0]+part_s[1][row][0]+part_s[2][row][0]+part_s[3][row][0];
      float s2 = part_s[0][row][1]+part_s[1][row][1]+part_s[2][row][1]+part_s[3][row][1];
      float mean = s1 * (1.f/H_);
      float var  = s2 * (1.f/H_) - mean*mean; var = fmaxf(var, 0.f);
      float rstd = rsqrtf(var + 1e-5f);
      int mk = masks[span];
      #pragma unroll
      for (int nf = 0; nf < 4; ++nf) {
        const int col = w*64 + nf*16 + ln16;
        float yv = (vals[mf][r][nf] - mean)*rstd*gv[nf] + bvv[nf];
        out[(size_t)span*H_ + col] = mk ? yv : 0.f;
      }
    }
}

extern "C" void kernel_launch(void* const* d_in, const int* in_sizes, int n_in,
                              void* d_out, int out_size, void* d_ws, size_t ws_size,
                              hipStream_t stream) {
  const float* tok      = (const float*)d_in[0];
  const int* span_ids   = (const int*)d_in[1];
  const int* span_masks = (const int*)d_in[2];
  const float* dq   = (const float*)d_in[4];
  const float* wq   = (const float*)d_in[5];
  const float* wk   = (const float*)d_in[6];
  const float* wv   = (const float*)d_in[7];
  const float* bqkv = (const float*)d_in[8];
  const float* wo   = (const float*)d_in[9];
  const float* bo   = (const float*)d_in[10];
  const float* lng  = (const float*)d_in[11];
  const float* lnb  = (const float*)d_in[12];
  const float* w1   = (const float*)d_in[13];
  const float* b1   = (const float*)d_in[14];
  const float* w2   = (const float*)d_in[15];
  const float* b2   = (const float*)d_in[16];

  float* ws    = (float*)d_ws;
  float* tr    = ws;                         // 524288 f
  float* qkvec = ws + 524288;                // 1024 f
  float* qbuf  = qkvec + 1024;               // 8 f
  float* lt    = qbuf + 8;                   // 8192 f (B*S*NH)
  unsigned short* ub = (unsigned short*)(lt + 8192);
  unsigned short* trbf   = ub;               // 524288
  unsigned short* wvt    = trbf + 524288;    // 65536
  unsigned short* wot    = wvt + 65536;      // 65536
  unsigned short* w1t    = wot + 65536;      // 262144
  unsigned short* w2t    = w1t + 262144;     // 262144
  unsigned short* pooled = w2t + 262144;     // (NSPAN/nb)*1024

  const size_t fixed_bytes = (size_t)(524288 + 1024 + 8 + 8192)*4
                           + (size_t)(524288 + 65536*2 + 262144*2)*2;
  int nb = 1;
  while (nb < 16 && fixed_bytes + (size_t)(NSPAN/nb)*1024*2 > ws_size) nb <<= 1;
  const int spans_b = NSPAN / nb;

  hipLaunchKernelGGL(prep_tr_kernel, dim3(B_*S_*H_/256), dim3(256), 0, stream, tok, tr, trbf);
  hipLaunchKernelGGL(prep_q_kernel, dim3(NH_), dim3(256), 0, stream,
                     dq, wq, wk, bqkv, qkvec, qbuf);
  hipLaunchKernelGGL(prep_logit_kernel, dim3(B_*S_/4), dim3(256), 0, stream,
                     tr, qkvec, qbuf, lt);
  hipLaunchKernelGGL(cast_bf16_kernel, dim3(65536/256), dim3(256), 0, stream, wv, wvt);
  hipLaunchKernelGGL(cast_bf16_kernel, dim3(65536/256), dim3(256), 0, stream, wo, wot);
  hipLaunchKernelGGL(prep_w1t_kernel, dim3(262144/256), dim3(256), 0, stream, w1, w1t);
  hipLaunchKernelGGL(prep_w2t_kernel, dim3(262144/256), dim3(256), 0, stream, w2, w2t);

  for (int bi = 0; bi < nb; ++bi) {
    const int span0 = bi * spans_b;
    hipLaunchKernelGGL(pool_kernel, dim3(spans_b/4), dim3(256), 0, stream,
                       trbf, lt, span_ids, span_masks, span0, pooled);
    hipLaunchKernelGGL(fused_gemm_kernel, dim3(spans_b/MT), dim3(256), 0, stream,
                       pooled, wvt, wot, bqkv, bo, dq, w1t, b1, w2t, b2,
                       lng, lnb, span_masks, span0, (float*)d_out);
  }
}